// Round 8
// baseline (262.896 us; speedup 1.0000x reference)
//
#include <hip/hip_runtime.h>
#include <hip/hip_bf16.h>
#include <math.h>

// Problem constants: B=4, L=1024, D=512, H=8, C=8, Dk=64
#define NB 4
#define NL 1024
#define ND 512
#define NH 8
#define NC 8
#define NDK 64

static constexpr float KL3_CONST = 115.36544595161891f; // -0.5*(1+ln0.01)*64, per clustering call

typedef __bf16 bf16x8 __attribute__((ext_vector_type(8)));
typedef float  f32x4v __attribute__((ext_vector_type(4)));
typedef unsigned short u16x4 __attribute__((ext_vector_type(4)));
typedef unsigned short u16x8 __attribute__((ext_vector_type(8)));

__device__ __forceinline__ unsigned short bf16u(float f) {
    return __builtin_bit_cast(unsigned short, (__bf16)f);
}

// ---------------------------------------------------------------------------
// GEMM body (shared by front and back kernels). 128x128 tile, BK=32, reg
// prefetch of next k-tile. out[row][col] = (Sum_k A[row][k]*W[col][k]+b)*s.
// ---------------------------------------------------------------------------
struct GemmArgs {
    const void* A; const float* W; const float* bias; void* out;
    float scale; int abf; int obf; int brow; int ostr; int vmap;
};

__device__ __forceinline__ void gemm_body(const GemmArgs& g, unsigned char* smem)
{
    unsigned short* As = (unsigned short*)smem;           // 128*40 u16 = 10240B
    unsigned short* Ws = (unsigned short*)(smem + 10240); // 10240B
    const int tid = threadIdx.x;
    const int n0 = (g.vmap ? blockIdx.y : blockIdx.x) * 128;
    const int m0 = (g.vmap ? blockIdx.x : blockIdx.y) * 128;

    const int kc = tid & 7;
    const int r0 = tid >> 3;
    const int wave = tid >> 6, lane = tid & 63;
    const int wm = wave >> 1, wn = wave & 1;
    const int r16 = lane & 15, quad = lane >> 4;

    f32x4v acc[4][4];
#pragma unroll
    for (int mi = 0; mi < 4; ++mi)
#pragma unroll
        for (int ni = 0; ni < 4; ++ni)
            acc[mi][ni] = (f32x4v){0.f, 0.f, 0.f, 0.f};

    u16x4 apre[4], wpre[4];
    auto ldA = [&](int k0, int rr) -> u16x4 {
        const int r = r0 + rr * 32;
        if (g.abf) {
            return *(const u16x4*)((const unsigned short*)g.A + (size_t)(m0 + r) * 512 + k0 + kc * 4);
        } else {
            const float4 av = *(const float4*)((const float*)g.A + (size_t)(m0 + r) * 512 + k0 + kc * 4);
            return (u16x4){ bf16u(av.x), bf16u(av.y), bf16u(av.z), bf16u(av.w) };
        }
    };
    auto ldW = [&](int k0, int rr) -> u16x4 {
        const int r = r0 + rr * 32;
        const float4 wv = *(const float4*)(g.W + (size_t)(n0 + r) * 512 + k0 + kc * 4);
        return (u16x4){ bf16u(wv.x), bf16u(wv.y), bf16u(wv.z), bf16u(wv.w) };
    };
#pragma unroll
    for (int rr = 0; rr < 4; ++rr) { apre[rr] = ldA(0, rr); wpre[rr] = ldW(0, rr); }

    for (int k0 = 0; k0 < 512; k0 += 32) {
        __syncthreads();
#pragma unroll
        for (int rr = 0; rr < 4; ++rr) {
            const int r = r0 + rr * 32;
            *(u16x4*)(As + r * 40 + kc * 4) = apre[rr];
            *(u16x4*)(Ws + r * 40 + kc * 4) = wpre[rr];
        }
        __syncthreads();
        if (k0 < 480) {
#pragma unroll
            for (int rr = 0; rr < 4; ++rr) { apre[rr] = ldA(k0 + 32, rr); wpre[rr] = ldW(k0 + 32, rr); }
        }

        bf16x8 af[4], bfr[4];
#pragma unroll
        for (int mi = 0; mi < 4; ++mi)
            af[mi] = *(const bf16x8*)(As + (wm * 64 + mi * 16 + r16) * 40 + quad * 8);
#pragma unroll
        for (int ni = 0; ni < 4; ++ni)
            bfr[ni] = *(const bf16x8*)(Ws + (wn * 64 + ni * 16 + r16) * 40 + quad * 8);
#pragma unroll
        for (int mi = 0; mi < 4; ++mi)
#pragma unroll
            for (int ni = 0; ni < 4; ++ni)
                acc[mi][ni] = __builtin_amdgcn_mfma_f32_16x16x32_bf16(af[mi], bfr[ni], acc[mi][ni], 0, 0, 0);
    }

#pragma unroll
    for (int ni = 0; ni < 4; ++ni) {
        const int col = n0 + wn * 64 + ni * 16 + r16;
        const float bcol = g.brow ? 0.f : g.bias[col];
#pragma unroll
        for (int mi = 0; mi < 4; ++mi) {
#pragma unroll
            for (int i = 0; i < 4; ++i) {
                const int row = m0 + wm * 64 + mi * 16 + quad * 4 + i;
                const float bv = g.brow ? g.bias[row] : bcol;
                const float v = (acc[mi][ni][i] + bv) * g.scale;
                if (g.obf) ((unsigned short*)g.out)[(size_t)row * g.ostr + col] = bf16u(v);
                else       ((float*)g.out)[(size_t)row * g.ostr + col] = v;
            }
        }
    }
}

// ---------------------------------------------------------------------------
// Cluster body: probs, per-block kl/div/Gram partials. 256 threads; block =
// (side=z-3, bh=blockIdx.y, 256 rows at blockIdx.x*256).
// ---------------------------------------------------------------------------
__device__ __forceinline__ void cluster_body(
    const float* __restrict__ query, const float* __restrict__ key,
    const float* __restrict__ tok_mu, const float* __restrict__ tok_log_var,
    const float* __restrict__ tok_log_prior,
    float* __restrict__ probs_q, float* __restrict__ probs_k,
    float* __restrict__ klp, float* __restrict__ divp, float* __restrict__ Gp,
    unsigned char* smem)
{
    float* mu_s    = (float*)smem;                 // 512 f
    float* iv_s    = (float*)(smem + 2048);        // 512 f
    float* Pl      = (float*)(smem + 4096);        // 256*9 f = 9216B
    float* Gpart   = (float*)(smem + 13312);       // 4*64 f = 1024B
    float* red_s   = (float*)(smem + 14336);       // 8 f
    float* lvsum_s = (float*)(smem + 14368);       // 8 f
    float* alpha_s = (float*)(smem + 14400);       // 8 f
    float* logp_s  = (float*)(smem + 14432);       // 8 f
    float* prior_s = (float*)(smem + 14464);       // 8 f

    const int tid  = threadIdx.x;
    const int bh   = blockIdx.y;
    const int b    = bh >> 3, h = bh & 7;
    const int side = blockIdx.z - 3;
    const int blocklin = side * 128 + bh * 4 + blockIdx.x;
    const float* src = side ? key : query;
    float* probs_out = side ? probs_k : probs_q;

    for (int i = tid; i < 512; i += 256) {
        mu_s[i] = tok_mu[h * 512 + i];
        float lv = tok_log_var[h * 512 + i];
        iv_s[i] = __expf(-lv);
    }
    if (tid < 8) {
        float ls = 0.f, al = 0.f;
        for (int d = 0; d < 64; ++d) {
            float lv = tok_log_var[(h * 8 + tid) * 64 + d];
            ls += lv;
            al += 0.01f * __expf(-lv) + lv;
        }
        lvsum_s[tid] = ls; alpha_s[tid] = al;
    }
    if (tid == 0) {
        float lp[8]; float mx = -1e30f;
        for (int c = 0; c < 8; ++c) { lp[c] = tok_log_prior[h * 8 + c]; mx = fmaxf(mx, lp[c]); }
        float se = 0.f;
        for (int c = 0; c < 8; ++c) se += __expf(lp[c] - mx);
        float lse = mx + __logf(se);
        for (int c = 0; c < 8; ++c) { logp_s[c] = lp[c] - lse; prior_s[c] = __expf(lp[c] - lse); }
    }
    __syncthreads();

    const int l = blockIdx.x * 256 + tid;
    const float4* xp = (const float4*)(src + ((size_t)(b * NL + l)) * ND + h * NDK);
    float4 xr[16];
#pragma unroll
    for (int i = 0; i < 16; ++i) xr[i] = xp[i];

    float ms[8];
#pragma unroll
    for (int c = 0; c < 8; ++c) {
        const float4* mc = (const float4*)(mu_s + c * 64);
        const float4* ic = (const float4*)(iv_s + c * 64);
        float s = 0.f;
#pragma unroll
        for (int i = 0; i < 16; ++i) {
            float4 m4 = mc[i], v4 = ic[i], x4 = xr[i];
            float dx = x4.x - m4.x; s = fmaf(dx * dx, v4.x, s);
            float dy = x4.y - m4.y; s = fmaf(dy * dy, v4.y, s);
            float dz = x4.z - m4.z; s = fmaf(dz * dz, v4.z, s);
            float dw = x4.w - m4.w; s = fmaf(dw * dw, v4.w, s);
        }
        ms[c] = s;
    }

    float lpdf[8]; float mx = -1e30f;
#pragma unroll
    for (int c = 0; c < 8; ++c) {
        lpdf[c] = -0.5f * (ms[c] + lvsum_s[c]) + logp_s[c];
        mx = fmaxf(mx, lpdf[c]);
    }
    float e[8]; float se = 0.f;
#pragma unroll
    for (int c = 0; c < 8; ++c) { e[c] = __expf(lpdf[c] - mx); se += e[c]; }
    float lse = __logf(se);
    float inv = 1.f / se;
    float p[8]; float kl1 = 0.f, kl2 = 0.f, sqq = 0.f;
#pragma unroll
    for (int c = 0; c < 8; ++c) {
        p[c] = e[c] * inv;
        float logprob = lpdf[c] - mx - lse;
        kl1 += prior_s[c] * (logp_s[c] - logprob);
        kl2 += p[c] * (ms[c] + alpha_s[c]);
        sqq = fmaf(p[c], p[c], sqq);
    }

    float* po = probs_out + ((size_t)((b * NH + h) * NL + l)) * NC;
    ((float4*)po)[0] = make_float4(p[0], p[1], p[2], p[3]);
    ((float4*)po)[1] = make_float4(p[4], p[5], p[6], p[7]);
#pragma unroll
    for (int c = 0; c < 8; ++c) Pl[tid * 9 + c] = p[c];

    float dterm = 1.25f * (sqq - 1.f) * (sqq - 1.f) - 0.75f * sqq * sqq;
    float klv = kl1 + 0.5f * kl2;
    __syncthreads();

    {
        int qt = tid >> 6, pos = tid & 63, c1 = pos >> 3, c2 = pos & 7;
        float g = 0.f;
        for (int i = 0; i < 64; ++i) {
            int ll = qt * 64 + i;
            g = fmaf(Pl[ll * 9 + c1], Pl[ll * 9 + c2], g);
        }
        Gpart[qt * 64 + pos] = g;
    }

#pragma unroll
    for (int o = 32; o > 0; o >>= 1) {
        klv   += __shfl_down(klv, o);
        dterm += __shfl_down(dterm, o);
    }
    if ((tid & 63) == 0) { red_s[tid >> 6] = klv; red_s[4 + (tid >> 6)] = dterm; }
    __syncthreads();
    if (tid == 0) {
        klp[blocklin]  = red_s[0] + red_s[1] + red_s[2] + red_s[3];
        divp[blocklin] = red_s[4] + red_s[5] + red_s[6] + red_s[7];
    }
    if (tid < 64)
        Gp[(size_t)blocklin * 64 + tid] =
            Gpart[tid] + Gpart[64 + tid] + Gpart[128 + tid] + Gpart[192 + tid];
}

// ---------------------------------------------------------------------------
// Front launch: z 0..2 = Q/K/V^T projections, z 3..4 = clustering (side 0/1).
// grid: (4, 32, 5)  block: 256
// ---------------------------------------------------------------------------
__global__ __launch_bounds__(256) void fused_front(
    GemmArgs g0, GemmArgs g1, GemmArgs g2,
    const float* query, const float* key,
    const float* tok_mu, const float* tok_log_var, const float* tok_log_prior,
    float* probs_q, float* probs_k,
    float* klp, float* divp, float* Gp)
{
    __shared__ alignas(16) unsigned char smem[20480];
    if (blockIdx.z >= 3) {
        cluster_body(query, key, tok_mu, tok_log_var, tok_log_prior,
                     probs_q, probs_k, klp, divp, Gp, smem);
        return;
    }
    GemmArgs g = (blockIdx.z == 0) ? g0 : ((blockIdx.z == 1) ? g1 : g2);
    gemm_body(g, smem);
}

// ---------------------------------------------------------------------------
// Back launch: z=0 O-projection, z=1 (block 0,0) finalize.
// ---------------------------------------------------------------------------
__device__ __forceinline__ void finalize_body(
    const float* __restrict__ klp, const float* __restrict__ divp,
    const float* __restrict__ Gp, float* __restrict__ out_tail)
{
    const int tid = threadIdx.x, b = tid >> 6, lane = tid & 63;
    float gsum = 0.f;
#pragma unroll
    for (int s = 0; s < 2; ++s)
#pragma unroll
        for (int h = 0; h < 8; ++h) {
            const int base = s * 128 + (b * 8 + h) * 4;
            float Ge = 0.f;
#pragma unroll
            for (int x = 0; x < 4; ++x) Ge += Gp[(size_t)(base + x) * 64 + lane];
            gsum = fmaf(Ge, Ge, gsum);
        }
    // 64 kl/div partials per b; one per lane
    const int s = lane >> 5, rem = lane & 31, h = rem >> 2, x = rem & 3;
    const int idx = s * 128 + (b * 8 + h) * 4 + x;
    float klv = klp[idx];
    float dvv = divp[idx];
#pragma unroll
    for (int o = 32; o > 0; o >>= 1) {
        gsum += __shfl_down(gsum, o);
        klv  += __shfl_down(klv, o);
        dvv  += __shfl_down(dvv, o);
    }
    if (lane == 0) {
        out_tail[b]     = klv * (1.0f / 8192.0f) + 2.0f * KL3_CONST;
        out_tail[4 + b] = (dvv + 0.75f * gsum) * (1.0f / 8388608.0f);
    }
}

__global__ __launch_bounds__(256) void fused_back(
    GemmArgs g0,
    const float* klp, const float* divp, const float* Gp, float* out_tail)
{
    __shared__ alignas(16) unsigned char smem[20480];
    if (blockIdx.z == 1) {
        if (blockIdx.x == 0 && blockIdx.y == 0)
            finalize_body(klp, divp, Gp, out_tail);
        return;
    }
    gemm_body(g0, smem);
}

// ---------------------------------------------------------------------------
// MFMA flash attention v6: K-split across 2 waves (512 keys each, 8 tiles),
// SOFTWARE-PIPELINED: K register double-buffered (prefetched a full tile
// ahead); pk/pm/V issued at tile top, consumed after the S-MFMAs / softmax.
// Zero per-tile barriers; one barrier for the 2-way (m,l,O) merge.
// grid: (64, 8, 4)  block: 128
// ---------------------------------------------------------------------------
#define APAD 72

__global__ __launch_bounds__(128) void attn_mfma6_kernel(
    const unsigned short* __restrict__ qp16, const unsigned short* __restrict__ kp16,
    const unsigned short* __restrict__ vtp16,
    const float* __restrict__ probs_q, const float* __restrict__ probs_k,
    const float* __restrict__ padding_mask, unsigned short* __restrict__ ao16)
{
    const int tid = threadIdx.x, lane = tid & 63, w = tid >> 6;
    const int r16 = lane & 15, quad = lane >> 4;
    const int b = blockIdx.z, h = blockIdx.y;
    const int qbase = blockIdx.x * 16;

    __shared__ alignas(16) unsigned short Ps[2][16 * APAD];
    __shared__ alignas(16) float Om[2][16 * 68];
    __shared__ float Ml[2][32];

    bf16x8 qa0, qa1;
    {
        const unsigned short* qrow = qp16 + ((size_t)(b * NL + qbase + r16)) * ND + h * NDK;
        qa0 = *(const bf16x8*)(qrow + quad * 8);
        qa1 = *(const bf16x8*)(qrow + 32 + quad * 8);
    }
    float pq[4][8];
#pragma unroll
    for (int i = 0; i < 4; ++i) {
        const float* pr = probs_q + ((size_t)((b * NH + h) * NL + qbase + quad * 4 + i)) * NC;
        float4 a = ((const float4*)pr)[0], c = ((const float4*)pr)[1];
        pq[i][0] = a.x; pq[i][1] = a.y; pq[i][2] = a.z; pq[i][3] = a.w;
        pq[i][4] = c.x; pq[i][5] = c.y; pq[i][6] = c.z; pq[i][7] = c.w;
    }

    f32x4v oacc[4];
#pragma unroll
    for (int n = 0; n < 4; ++n) oacc[n] = (f32x4v){0.f, 0.f, 0.f, 0.f};
    float m_i[4] = {-1e30f, -1e30f, -1e30f, -1e30f};
    float l_i[4] = {0.f, 0.f, 0.f, 0.f};

    const unsigned short* kbase = kp16 + (size_t)b * NL * ND + h * NDK;
    const unsigned short* vbase = vtp16 + (size_t)(h * NDK) * (NB * NL) + b * NL;
    const float* pkb = probs_k + ((size_t)(b * NH + h)) * NL * NC;
    const float* pmb = padding_mask + b * NL;
    const int kw0 = w * 512;

    // prologue: K tile 0 into the current buffer
    bf16x8 kc0[4], kc1[4], kn0[4], kn1[4];
#pragma unroll
    for (int t = 0; t < 4; ++t) {
        const unsigned short* kr = kbase + (size_t)(kw0 + t * 16 + r16) * ND;
        kc0[t] = *(const bf16x8*)(kr + quad * 8);
        kc1[t] = *(const bf16x8*)(kr + 32 + quad * 8);
    }

#pragma unroll
    for (int kt = 0; kt < 8; ++kt) {
        const int key0 = kw0 + kt * 64;

        // prefetch next K tile (consumed next iteration)
        if (kt < 7) {
#pragma unroll
            for (int t = 0; t < 4; ++t) {
                const unsigned short* kr = kbase + (size_t)(key0 + 64 + t * 16 + r16) * ND;
                kn0[t] = *(const bf16x8*)(kr + quad * 8);
                kn1[t] = *(const bf16x8*)(kr + 32 + quad * 8);
            }
        }
        // issue pk/pm/V loads now; consumed after the S-MFMAs / softmax
        float4 pk0[4], pk1[4]; float pmv[4];
#pragma unroll
        for (int t = 0; t < 4; ++t) {
            const int keyg = key0 + t * 16 + r16;
            pk0[t] = *(const float4*)(pkb + (size_t)keyg * NC);
            pk1[t] = *(const float4*)(pkb + (size_t)keyg * NC + 4);
            pmv[t] = pmb[keyg];
        }
        bf16x8 vb0[4], vb1[4];
#pragma unroll
        for (int n = 0; n < 4; ++n) {
            const unsigned short* vr = vbase + (size_t)(n * 16 + r16) * (NB * NL) + key0;
            vb0[n] = *(const bf16x8*)(vr + quad * 8);
            vb1[n] = *(const bf16x8*)(vr + 32 + quad * 8);
        }

        // S = Q K^T (current K buffer)
        f32x4v sacc[4];
#pragma unroll
        for (int t = 0; t < 4; ++t) {
            sacc[t] = (f32x4v){0.f, 0.f, 0.f, 0.f};
            sacc[t] = __builtin_amdgcn_mfma_f32_16x16x32_bf16(qa0, kc0[t], sacc[t], 0, 0, 0);
            sacc[t] = __builtin_amdgcn_mfma_f32_16x16x32_bf16(qa1, kc1[t], sacc[t], 0, 0, 0);
        }

        // sim (fp32: enters exponent x10000) + mask
        float sc[4][4], wgt[4][4];
#pragma unroll
        for (int t = 0; t < 4; ++t) {
#pragma unroll
            for (int i = 0; i < 4; ++i) {
                float sim = pq[i][0] * pk0[t].x + pq[i][1] * pk0[t].y
                          + pq[i][2] * pk0[t].z + pq[i][3] * pk0[t].w
                          + pq[i][4] * pk1[t].x + pq[i][5] * pk1[t].y
                          + pq[i][6] * pk1[t].z + pq[i][7] * pk1[t].w;
                float cm = 1.f - sim + pmv[t];
                cm = fminf(fmaxf(cm, 0.f), 1.f);
                sc[t][i] = sacc[t][i] - 10000.f * cm;
                wgt[t][i] = 1.f - cm;
            }
        }

        // online softmax (row stats over the 16-lane quad group)
        float mx[4];
#pragma unroll
        for (int i = 0; i < 4; ++i)
            mx[i] = fmaxf(fmaxf(sc[0][i], sc[1][i]), fmaxf(sc[2][i], sc[3][i]));
#pragma unroll
        for (int o = 1; o < 16; o <<= 1) {
#pragma unroll
            for (int i = 0; i < 4; ++i) mx[i] = fmaxf(mx[i], __shfl_xor(mx[i], o));
        }
        float rr[4];
#pragma unroll
        for (int i = 0; i < 4; ++i) {
            const float mnew = fmaxf(m_i[i], mx[i]);
            rr[i] = __expf(m_i[i] - mnew);
            m_i[i] = mnew;
            l_i[i] *= rr[i];
        }
#pragma unroll
        for (int n = 0; n < 4; ++n) {
            oacc[n][0] *= rr[0]; oacc[n][1] *= rr[1];
            oacc[n][2] *= rr[2]; oacc[n][3] *= rr[3];
        }
        float lad[4] = {0.f, 0.f, 0.f, 0.f};
#pragma unroll
        for (int t = 0; t < 4; ++t) {
#pragma unroll
            for (int i = 0; i < 4; ++i) {
                const float p = __expf(sc[t][i] - m_i[i]);
                lad[i] += p;
                Ps[w][(quad * 4 + i) * APAD + t * 16 + r16] = bf16u(p * wgt[t][i]);
            }
        }
#pragma unroll
        for (int o = 1; o < 16; o <<= 1) {
#pragma unroll
            for (int i = 0; i < 4; ++i) lad[i] += __shfl_xor(lad[i], o);
        }
#pragma unroll
        for (int i = 0; i < 4; ++i) l_i[i] += lad[i];

        // O += P' V
        bf16x8 pa0 = *(const bf16x8*)(Ps[w] + r16 * APAD + quad * 8);
        bf16x8 pa1 = *(const bf16x8*)(Ps[w] + r16 * APAD + 32 + quad * 8);
#pragma unroll
        for (int n = 0; n < 4; ++n) {
            oacc[n] = __builtin_amdgcn_mfma_f32_16x16x32_bf16(pa0, vb0[n], oacc[n], 0, 0, 0);
            oacc[n] = __builtin_amdgcn_mfma_f32_16x16x32_bf16(pa1, vb1[n], oacc[n], 0, 0, 0);
        }

        // rotate K buffers (renamed away by full unroll)
#pragma unroll
        for (int t = 0; t < 4; ++t) { kc0[t] = kn0[t]; kc1[t] = kn1[t]; }
    }

    // ---- publish per-wave partials, merge 2 K-splits ----
#pragma unroll
    for (int i = 0; i < 4; ++i)
#pragma unroll
        for (int n = 0; n < 4; ++n)
            Om[w][(quad * 4 + i) * 68 + n * 16 + r16] = oacc[n][i];
    if (r16 == 0) {
#pragma unroll
        for (int i = 0; i < 4; ++i) {
            Ml[w][quad * 4 + i]      = m_i[i];
            Ml[w][16 + quad * 4 + i] = l_i[i];
        }
    }
    __syncthreads();

    {
        const int r = tid >> 3, d0 = (tid & 7) * 8;
        const float M = fmaxf(Ml[0][r], Ml[1][r]);
        float lsum = 0.f;
        float o[8] = {0.f, 0.f, 0.f, 0.f, 0.f, 0.f, 0.f, 0.f};
#pragma unroll
        for (int wv = 0; wv < 2; ++wv) {
            const float e = __expf(Ml[wv][r] - M);
            lsum = fmaf(Ml[wv][16 + r], e, lsum);
            const float* sp = &Om[wv][r * 68 + d0];
#pragma unroll
            for (int j = 0; j < 8; ++j) o[j] = fmaf(sp[j], e, o[j]);
        }
        const float inv = 1.f / lsum;
        unsigned short* orow = ao16 + ((size_t)(b * NL + qbase + r)) * ND + h * NDK + d0;
        u16x8 ov = { bf16u(o[0] * inv), bf16u(o[1] * inv), bf16u(o[2] * inv), bf16u(o[3] * inv),
                     bf16u(o[4] * inv), bf16u(o[5] * inv), bf16u(o[6] * inv), bf16u(o[7] * inv) };
        *(u16x8*)orow = ov;
    }
}

// ---------------------------------------------------------------------------
extern "C" void kernel_launch(void* const* d_in, const int* in_sizes, int n_in,
                              void* d_out, int out_size, void* d_ws, size_t ws_size,
                              hipStream_t stream)
{
    const float* query        = (const float*)d_in[0];
    const float* key          = (const float*)d_in[1];
    const float* value        = (const float*)d_in[2];
    const float* padding_mask = (const float*)d_in[3];
    const float* Wq = (const float*)d_in[4];
    const float* bq = (const float*)d_in[5];
    const float* Wk = (const float*)d_in[6];
    const float* bk = (const float*)d_in[7];
    const float* Wv = (const float*)d_in[8];
    const float* bv = (const float*)d_in[9];
    const float* Wo = (const float*)d_in[10];
    const float* bo = (const float*)d_in[11];
    const float* tok_mu        = (const float*)d_in[12];
    const float* tok_log_var   = (const float*)d_in[13];
    const float* tok_log_prior = (const float*)d_in[14];

    float* ws = (float*)d_ws;
    const size_t NMAT = (size_t)NB * NL * ND;        // 2097152 elements
    const size_t NH16 = NMAT / 2;                    // bf16 matrix in float-slots
    unsigned short* qp16  = (unsigned short*)ws;
    unsigned short* kp16  = (unsigned short*)(ws + NH16);
    unsigned short* vtp16 = (unsigned short*)(ws + 2 * NH16);
    unsigned short* ao16  = (unsigned short*)(ws + 3 * NH16);
    float* probs_q = ws + 4 * NH16;                  // 262144 floats each
    float* probs_k = probs_q + (size_t)NB * NH * NL * NC;
    float* klp     = probs_k + (size_t)NB * NH * NL * NC;   // 256
    float* divp    = klp + 256;                              // 256
    float* Gp      = divp + 256;                             // 256*64

    // ONE launch: Q-proj, K-proj, V^T-proj (z 0..2) + clustering (z 3..4).
    // GEMMs read fp32 query/key/value with inline bf16 cvt -> independent of
    // cluster, so they co-schedule on the CUs within the launch.
    GemmArgs gq {query, Wq, bq, qp16, 0.125f, 0, 1, 0, 512, 0};
    GemmArgs gk {key,   Wk, bk, kp16, 1.f,    0, 1, 0, 512, 0};
    GemmArgs gvt{Wv, value, bv, vtp16, 1.f,   0, 1, 1, 4096, 1};
    fused_front<<<dim3(4, 32, 5), 256, 0, stream>>>(
        gq, gk, gvt, query, key, tok_mu, tok_log_var, tok_log_prior,
        probs_q, probs_k, klp, divp, Gp);

    attn_mfma6_kernel<<<dim3(64, NH, NB), 128, 0, stream>>>(
        qp16, kp16, vtp16, probs_q, probs_k, padding_mask, ao16);

    // ONE launch: O-proj (z=0) + finalize (z=1, block 0,0)
    GemmArgs go{ao16, Wo, bo, d_out, 1.f, 1, 0, 0, 512, 0};
    fused_back<<<dim3(4, 32, 2), 256, 0, stream>>>(
        go, klp, divp, Gp, (float*)d_out + NMAT);
}

// Round 9
// 241.902 us; speedup vs baseline: 1.0868x; 1.0868x over previous
//
#include <hip/hip_runtime.h>
#include <hip/hip_bf16.h>
#include <math.h>

// Problem constants: B=4, L=1024, D=512, H=8, C=8, Dk=64
#define NB 4
#define NL 1024
#define ND 512
#define NH 8
#define NC 8
#define NDK 64

static constexpr float KL3_CONST = 115.36544595161891f; // -0.5*(1+ln0.01)*64, per clustering call

typedef __bf16 bf16x8 __attribute__((ext_vector_type(8)));
typedef float  f32x4v __attribute__((ext_vector_type(4)));
typedef unsigned short u16x4 __attribute__((ext_vector_type(4)));
typedef unsigned short u16x8 __attribute__((ext_vector_type(8)));

__device__ __forceinline__ unsigned short bf16u(float f) {
    return __builtin_bit_cast(unsigned short, (__bf16)f);
}

// ---------------------------------------------------------------------------
// GEMM body. 128x128 tile, BK=32, reg prefetch of next k-tile.
// out[row][col] = (Sum_k A[row][k]*W[col][k] + bias) * scale
// ---------------------------------------------------------------------------
struct GemmArgs {
    const void* A; const float* W; const float* bias; void* out;
    float scale; int abf; int obf; int brow; int ostr; int vmap;
};

__device__ __forceinline__ void gemm_body(const GemmArgs& g, unsigned char* smem)
{
    unsigned short* As = (unsigned short*)smem;           // 128*40 u16
    unsigned short* Ws = (unsigned short*)(smem + 10240);
    const int tid = threadIdx.x;
    const int n0 = (g.vmap ? blockIdx.y : blockIdx.x) * 128;
    const int m0 = (g.vmap ? blockIdx.x : blockIdx.y) * 128;

    const int kc = tid & 7;
    const int r0 = tid >> 3;
    const int wave = tid >> 6, lane = tid & 63;
    const int wm = wave >> 1, wn = wave & 1;
    const int r16 = lane & 15, quad = lane >> 4;

    f32x4v acc[4][4];
#pragma unroll
    for (int mi = 0; mi < 4; ++mi)
#pragma unroll
        for (int ni = 0; ni < 4; ++ni)
            acc[mi][ni] = (f32x4v){0.f, 0.f, 0.f, 0.f};

    u16x4 apre[4], wpre[4];
    auto ldA = [&](int k0, int rr) -> u16x4 {
        const int r = r0 + rr * 32;
        if (g.abf) {
            return *(const u16x4*)((const unsigned short*)g.A + (size_t)(m0 + r) * 512 + k0 + kc * 4);
        } else {
            const float4 av = *(const float4*)((const float*)g.A + (size_t)(m0 + r) * 512 + k0 + kc * 4);
            return (u16x4){ bf16u(av.x), bf16u(av.y), bf16u(av.z), bf16u(av.w) };
        }
    };
    auto ldW = [&](int k0, int rr) -> u16x4 {
        const int r = r0 + rr * 32;
        const float4 wv = *(const float4*)(g.W + (size_t)(n0 + r) * 512 + k0 + kc * 4);
        return (u16x4){ bf16u(wv.x), bf16u(wv.y), bf16u(wv.z), bf16u(wv.w) };
    };
#pragma unroll
    for (int rr = 0; rr < 4; ++rr) { apre[rr] = ldA(0, rr); wpre[rr] = ldW(0, rr); }

    for (int k0 = 0; k0 < 512; k0 += 32) {
        __syncthreads();
#pragma unroll
        for (int rr = 0; rr < 4; ++rr) {
            const int r = r0 + rr * 32;
            *(u16x4*)(As + r * 40 + kc * 4) = apre[rr];
            *(u16x4*)(Ws + r * 40 + kc * 4) = wpre[rr];
        }
        __syncthreads();
        if (k0 < 480) {
#pragma unroll
            for (int rr = 0; rr < 4; ++rr) { apre[rr] = ldA(k0 + 32, rr); wpre[rr] = ldW(k0 + 32, rr); }
        }

        bf16x8 af[4], bfr[4];
#pragma unroll
        for (int mi = 0; mi < 4; ++mi)
            af[mi] = *(const bf16x8*)(As + (wm * 64 + mi * 16 + r16) * 40 + quad * 8);
#pragma unroll
        for (int ni = 0; ni < 4; ++ni)
            bfr[ni] = *(const bf16x8*)(Ws + (wn * 64 + ni * 16 + r16) * 40 + quad * 8);
#pragma unroll
        for (int mi = 0; mi < 4; ++mi)
#pragma unroll
            for (int ni = 0; ni < 4; ++ni)
                acc[mi][ni] = __builtin_amdgcn_mfma_f32_16x16x32_bf16(af[mi], bfr[ni], acc[mi][ni], 0, 0, 0);
    }

#pragma unroll
    for (int ni = 0; ni < 4; ++ni) {
        const int col = n0 + wn * 64 + ni * 16 + r16;
        const float bcol = g.brow ? 0.f : g.bias[col];
#pragma unroll
        for (int mi = 0; mi < 4; ++mi) {
#pragma unroll
            for (int i = 0; i < 4; ++i) {
                const int row = m0 + wm * 64 + mi * 16 + quad * 4 + i;
                const float bv = g.brow ? g.bias[row] : bcol;
                const float v = (acc[mi][ni][i] + bv) * g.scale;
                if (g.obf) ((unsigned short*)g.out)[(size_t)row * g.ostr + col] = bf16u(v);
                else       ((float*)g.out)[(size_t)row * g.ostr + col] = v;
            }
        }
    }
}

// ---------------------------------------------------------------------------
// Cluster body: kl/div/Gram partials + PACKED hi/lo bf16 probs for the
// MFMA-sim (pqx: [h0..7,l0..7] per (b,h,l); pkx same; reader offsets select
// the A-pattern [h l h l] / B-pattern [h h l l]).
// ---------------------------------------------------------------------------
__device__ __forceinline__ void cluster_body(
    const float* __restrict__ query, const float* __restrict__ key,
    const float* __restrict__ tok_mu, const float* __restrict__ tok_log_var,
    const float* __restrict__ tok_log_prior,
    unsigned short* __restrict__ pqx, unsigned short* __restrict__ pkx,
    float* __restrict__ klp, float* __restrict__ divp, float* __restrict__ Gp,
    unsigned char* smem)
{
    float* mu_s    = (float*)smem;                 // 512
    float* iv_s    = (float*)(smem + 2048);        // 512
    float* Pl      = (float*)(smem + 4096);        // 256*9
    float* Gpart   = (float*)(smem + 13312);       // 4*64
    float* red_s   = (float*)(smem + 14336);       // 8
    float* lvsum_s = (float*)(smem + 14368);
    float* alpha_s = (float*)(smem + 14400);
    float* logp_s  = (float*)(smem + 14432);
    float* prior_s = (float*)(smem + 14464);

    const int tid  = threadIdx.x;
    const int bh   = blockIdx.y;
    const int b    = bh >> 3, h = bh & 7;
    const int side = blockIdx.z - 3;
    const int blocklin = side * 128 + bh * 4 + blockIdx.x;
    const float* src = side ? key : query;
    unsigned short* pxx = side ? pkx : pqx;

    for (int i = tid; i < 512; i += 256) {
        mu_s[i] = tok_mu[h * 512 + i];
        float lv = tok_log_var[h * 512 + i];
        iv_s[i] = __expf(-lv);
    }
    if (tid < 8) {
        float ls = 0.f, al = 0.f;
        for (int d = 0; d < 64; ++d) {
            float lv = tok_log_var[(h * 8 + tid) * 64 + d];
            ls += lv;
            al += 0.01f * __expf(-lv) + lv;
        }
        lvsum_s[tid] = ls; alpha_s[tid] = al;
    }
    if (tid == 0) {
        float lp[8]; float mx = -1e30f;
        for (int c = 0; c < 8; ++c) { lp[c] = tok_log_prior[h * 8 + c]; mx = fmaxf(mx, lp[c]); }
        float se = 0.f;
        for (int c = 0; c < 8; ++c) se += __expf(lp[c] - mx);
        float lse = mx + __logf(se);
        for (int c = 0; c < 8; ++c) { logp_s[c] = lp[c] - lse; prior_s[c] = __expf(lp[c] - lse); }
    }
    __syncthreads();

    const int l = blockIdx.x * 256 + tid;
    const float4* xp = (const float4*)(src + ((size_t)(b * NL + l)) * ND + h * NDK);
    float4 xr[16];
#pragma unroll
    for (int i = 0; i < 16; ++i) xr[i] = xp[i];

    float ms[8];
#pragma unroll
    for (int c = 0; c < 8; ++c) {
        const float4* mc = (const float4*)(mu_s + c * 64);
        const float4* ic = (const float4*)(iv_s + c * 64);
        float s = 0.f;
#pragma unroll
        for (int i = 0; i < 16; ++i) {
            float4 m4 = mc[i], v4 = ic[i], x4 = xr[i];
            float dx = x4.x - m4.x; s = fmaf(dx * dx, v4.x, s);
            float dy = x4.y - m4.y; s = fmaf(dy * dy, v4.y, s);
            float dz = x4.z - m4.z; s = fmaf(dz * dz, v4.z, s);
            float dw = x4.w - m4.w; s = fmaf(dw * dw, v4.w, s);
        }
        ms[c] = s;
    }

    float lpdf[8]; float mx = -1e30f;
#pragma unroll
    for (int c = 0; c < 8; ++c) {
        lpdf[c] = -0.5f * (ms[c] + lvsum_s[c]) + logp_s[c];
        mx = fmaxf(mx, lpdf[c]);
    }
    float e[8]; float se = 0.f;
#pragma unroll
    for (int c = 0; c < 8; ++c) { e[c] = __expf(lpdf[c] - mx); se += e[c]; }
    float lse = __logf(se);
    float inv = 1.f / se;
    float p[8]; float kl1 = 0.f, kl2 = 0.f, sqq = 0.f;
#pragma unroll
    for (int c = 0; c < 8; ++c) {
        p[c] = e[c] * inv;
        float logprob = lpdf[c] - mx - lse;
        kl1 += prior_s[c] * (logp_s[c] - logprob);
        kl2 += p[c] * (ms[c] + alpha_s[c]);
        sqq = fmaf(p[c], p[c], sqq);
    }

    // packed hi/lo emit (exact two-term split of each prob)
    {
        unsigned short hu[8], lu[8];
#pragma unroll
        for (int c = 0; c < 8; ++c) {
            hu[c] = bf16u(p[c]);
            float hf = (float)__builtin_bit_cast(__bf16, hu[c]);
            lu[c] = bf16u(p[c] - hf);
        }
        unsigned short* dst = pxx + ((size_t)(bh * NL + l)) * 16;
        *(u16x8*)dst       = (u16x8){hu[0],hu[1],hu[2],hu[3],hu[4],hu[5],hu[6],hu[7]};
        *(u16x8*)(dst + 8) = (u16x8){lu[0],lu[1],lu[2],lu[3],lu[4],lu[5],lu[6],lu[7]};
    }
#pragma unroll
    for (int c = 0; c < 8; ++c) Pl[tid * 9 + c] = p[c];

    float dterm = 1.25f * (sqq - 1.f) * (sqq - 1.f) - 0.75f * sqq * sqq;
    float klv = kl1 + 0.5f * kl2;
    __syncthreads();

    {
        int qt = tid >> 6, pos = tid & 63, c1 = pos >> 3, c2 = pos & 7;
        float g = 0.f;
        for (int i = 0; i < 64; ++i) {
            int ll = qt * 64 + i;
            g = fmaf(Pl[ll * 9 + c1], Pl[ll * 9 + c2], g);
        }
        Gpart[qt * 64 + pos] = g;
    }

#pragma unroll
    for (int o = 32; o > 0; o >>= 1) {
        klv   += __shfl_down(klv, o);
        dterm += __shfl_down(dterm, o);
    }
    if ((tid & 63) == 0) { red_s[tid >> 6] = klv; red_s[4 + (tid >> 6)] = dterm; }
    __syncthreads();
    if (tid == 0) {
        klp[blocklin]  = red_s[0] + red_s[1] + red_s[2] + red_s[3];
        divp[blocklin] = red_s[4] + red_s[5] + red_s[6] + red_s[7];
    }
    if (tid < 64)
        Gp[(size_t)blocklin * 64 + tid] =
            Gpart[tid] + Gpart[64 + tid] + Gpart[128 + tid] + Gpart[192 + tid];
}

// ---------------------------------------------------------------------------
// Front launch: z 0..2 = Q/K/V^T projections, z 3..4 = clustering.
// grid: (4, 32, 5)  block: 256
// ---------------------------------------------------------------------------
__global__ __launch_bounds__(256) void fused_front(
    GemmArgs g0, GemmArgs g1, GemmArgs g2,
    const float* query, const float* key,
    const float* tok_mu, const float* tok_log_var, const float* tok_log_prior,
    unsigned short* pqx, unsigned short* pkx,
    float* klp, float* divp, float* Gp)
{
    __shared__ alignas(16) unsigned char smem[20480];
    if (blockIdx.z >= 3) {
        cluster_body(query, key, tok_mu, tok_log_var, tok_log_prior,
                     pqx, pkx, klp, divp, Gp, smem);
        return;
    }
    GemmArgs g = (blockIdx.z == 0) ? g0 : ((blockIdx.z == 1) ? g1 : g2);
    gemm_body(g, smem);
}

// ---------------------------------------------------------------------------
// MFMA flash attention v7: 64 q-rows/block (4 waves x 16-row strips), K-SPLIT
// x2 ACROSS BLOCKS (512 keys each, 4 iters of KB=128). Ks LDS-staged
// (cooperative bulk loads); V^T and packed-prob B-frags direct from global
// (contiguous 16B, L2-hot). sim via one K=32 bf16 MFMA per 16-key subtile
// (hi/lo packed operands; pm folded into C-init). Partial (m,l,O) in fp32 to
// workspace; merged by merge_fin_kernel. grid: (16, 8, 8)  block: 256
// ---------------------------------------------------------------------------
__global__ __launch_bounds__(256) void attn_mfma7_kernel(
    const unsigned short* __restrict__ qp16, const unsigned short* __restrict__ kp16,
    const unsigned short* __restrict__ vt16,
    const unsigned short* __restrict__ pqx, const unsigned short* __restrict__ pkx,
    const float* __restrict__ pmask,
    float* __restrict__ pO, float* __restrict__ pML)
{
    const int tid = threadIdx.x, lane = tid & 63, w = tid >> 6;
    const int r16 = lane & 15, quad = lane >> 4;
    const int qt = blockIdx.x, h = blockIdx.y;
    const int b = blockIdx.z >> 1, s = blockIdx.z & 1;
    const int bh = b * 8 + h;
    const int sb = bh * 16 + qt;

    __shared__ alignas(16) unsigned short Ks[128 * 72];
    __shared__ alignas(16) unsigned short Ps[4][16 * 136];
    __shared__ alignas(16) float pm_s[512];

    {   // stage this split's padding-mask range once
        *(float2*)(pm_s + tid * 2) = *(const float2*)(pmask + b * NL + s * 512 + tid * 2);
    }

    const int qrow = qt * 64 + w * 16 + r16;
    bf16x8 qa0, qa1, pqA;
    {
        const unsigned short* qr = qp16 + ((size_t)(b * NL + qrow)) * ND + h * NDK;
        qa0 = *(const bf16x8*)(qr + quad * 8);
        qa1 = *(const bf16x8*)(qr + 32 + quad * 8);
        pqA = *(const bf16x8*)(pqx + ((size_t)(bh * NL + qrow)) * 16 + (quad & 1) * 8);
    }

    f32x4v oacc[4];
#pragma unroll
    for (int n = 0; n < 4; ++n) oacc[n] = (f32x4v){0.f, 0.f, 0.f, 0.f};
    float m_i[4] = {-1e30f, -1e30f, -1e30f, -1e30f};
    float l_i[4] = {0.f, 0.f, 0.f, 0.f};

    for (int kt = 0; kt < 4; ++kt) {
        const int key0 = s * 512 + kt * 128;
        __syncthreads();   // prev-iter Ks reads complete
#pragma unroll
        for (int j = 0; j < 4; ++j) {
            const int c = j * 256 + tid;         // 1024 u16x8 chunks
            const int key = c >> 3, c8 = c & 7;
            u16x8 kv = *(const u16x8*)(kp16 + ((size_t)(b * NL + key0 + key)) * ND + h * NDK + c8 * 8);
            *(u16x8*)(Ks + key * 72 + c8 * 8) = kv;
        }
        __syncthreads();

        // packed-prob B-frags + pm (issued up front, consumed by the MFMAs)
        bf16x8 pkf[8]; float pmv[8];
#pragma unroll
        for (int t = 0; t < 8; ++t) {
            const int keyg = key0 + t * 16 + r16;
            pkf[t] = *(const bf16x8*)(pkx + ((size_t)(bh * NL + keyg)) * 16 + (quad >> 1) * 8);
            pmv[t] = pm_s[kt * 128 + t * 16 + r16];
        }

        float sc[8][4], wgt[8][4];
#pragma unroll
        for (int t = 0; t < 8; ++t) {
            bf16x8 kb0 = *(const bf16x8*)(Ks + (t * 16 + r16) * 72 + quad * 8);
            bf16x8 kb1 = *(const bf16x8*)(Ks + (t * 16 + r16) * 72 + 32 + quad * 8);
            f32x4v sa = (f32x4v){0.f, 0.f, 0.f, 0.f};
            sa = __builtin_amdgcn_mfma_f32_16x16x32_bf16(qa0, kb0, sa, 0, 0, 0);
            sa = __builtin_amdgcn_mfma_f32_16x16x32_bf16(qa1, kb1, sa, 0, 0, 0);
            f32x4v ma = (f32x4v){-pmv[t], -pmv[t], -pmv[t], -pmv[t]};
            ma = __builtin_amdgcn_mfma_f32_16x16x32_bf16(pqA, pkf[t], ma, 0, 0, 0);
#pragma unroll
            for (int i = 0; i < 4; ++i) {
                float cm = 1.f - ma[i];           // = 1 - sim + pm
                cm = fminf(fmaxf(cm, 0.f), 1.f);
                sc[t][i]  = sa[i] - 10000.f * cm;
                wgt[t][i] = 1.f - cm;
            }
        }

        // online softmax over 128 keys (local 8-way max, then quad-group shfl)
        float mx[4];
#pragma unroll
        for (int i = 0; i < 4; ++i) {
            float m0 = fmaxf(fmaxf(sc[0][i], sc[1][i]), fmaxf(sc[2][i], sc[3][i]));
            float m1 = fmaxf(fmaxf(sc[4][i], sc[5][i]), fmaxf(sc[6][i], sc[7][i]));
            mx[i] = fmaxf(m0, m1);
        }
#pragma unroll
        for (int o = 1; o < 16; o <<= 1) {
#pragma unroll
            for (int i = 0; i < 4; ++i) mx[i] = fmaxf(mx[i], __shfl_xor(mx[i], o));
        }
        float rr[4];
#pragma unroll
        for (int i = 0; i < 4; ++i) {
            const float mnew = fmaxf(m_i[i], mx[i]);
            rr[i] = __expf(m_i[i] - mnew);
            m_i[i] = mnew;
            l_i[i] *= rr[i];
        }
#pragma unroll
        for (int n = 0; n < 4; ++n) {
            oacc[n][0] *= rr[0]; oacc[n][1] *= rr[1];
            oacc[n][2] *= rr[2]; oacc[n][3] *= rr[3];
        }
        float lad[4] = {0.f, 0.f, 0.f, 0.f};
#pragma unroll
        for (int t = 0; t < 8; ++t) {
#pragma unroll
            for (int i = 0; i < 4; ++i) {
                const float p = __expf(sc[t][i] - m_i[i]);
                lad[i] += p;
                Ps[w][(quad * 4 + i) * 136 + t * 16 + r16] = bf16u(p * wgt[t][i]);
            }
        }
#pragma unroll
        for (int o = 1; o < 16; o <<= 1) {
#pragma unroll
            for (int i = 0; i < 4; ++i) lad[i] += __shfl_xor(lad[i], o);
        }
#pragma unroll
        for (int i = 0; i < 4; ++i) l_i[i] += lad[i];

        // O += P' V   (A from per-wave Ps; V^T B-frags direct from global)
#pragma unroll
        for (int c = 0; c < 4; ++c) {
            bf16x8 pa = *(const bf16x8*)(Ps[w] + r16 * 136 + c * 32 + quad * 8);
#pragma unroll
            for (int n = 0; n < 4; ++n) {
                const unsigned short* vr = vt16
                    + ((size_t)(h * NDK + n * 16 + r16)) * (NB * NL)
                    + b * NL + key0 + c * 32 + quad * 8;
                bf16x8 vb = *(const bf16x8*)vr;
                oacc[n] = __builtin_amdgcn_mfma_f32_16x16x32_bf16(pa, vb, oacc[n], 0, 0, 0);
            }
        }
    }

    // ---- write fp32 partials (merged by merge_fin_kernel) ----
    float* po = pO + (size_t)sb * 8192 + s * 4096;
#pragma unroll
    for (int i = 0; i < 4; ++i) {
        const int row = w * 16 + quad * 4 + i;
#pragma unroll
        for (int n = 0; n < 4; ++n)
            po[row * 64 + n * 16 + r16] = oacc[n][i];
    }
    if (r16 == 0) {
        float* pm2 = pML + (size_t)sb * 256 + s * 128;
#pragma unroll
        for (int i = 0; i < 4; ++i) {
            const int row = w * 16 + quad * 4 + i;
            pm2[row * 2]     = m_i[i];
            pm2[row * 2 + 1] = l_i[i];
        }
    }
}

// ---------------------------------------------------------------------------
// Merge the 2 K-splits (blocks 0..255) + finalize scalars (block 256).
// ---------------------------------------------------------------------------
__device__ __forceinline__ void finalize_body(
    const float* __restrict__ klp, const float* __restrict__ divp,
    const float* __restrict__ Gp, float* __restrict__ out_tail)
{
    const int tid = threadIdx.x, b = tid >> 6, lane = tid & 63;
    float gsum = 0.f;
#pragma unroll
    for (int s = 0; s < 2; ++s)
#pragma unroll
        for (int h = 0; h < 8; ++h) {
            const int base = s * 128 + (b * 8 + h) * 4;
            float Ge = 0.f;
#pragma unroll
            for (int x = 0; x < 4; ++x) Ge += Gp[(size_t)(base + x) * 64 + lane];
            gsum = fmaf(Ge, Ge, gsum);
        }
    const int s = lane >> 5, rem = lane & 31, h = rem >> 2, x = rem & 3;
    const int idx = s * 128 + (b * 8 + h) * 4 + x;
    float klv = klp[idx];
    float dvv = divp[idx];
#pragma unroll
    for (int o = 32; o > 0; o >>= 1) {
        gsum += __shfl_down(gsum, o);
        klv  += __shfl_down(klv, o);
        dvv  += __shfl_down(dvv, o);
    }
    if (lane == 0) {
        out_tail[b]     = klv * (1.0f / 8192.0f) + 2.0f * KL3_CONST;
        out_tail[4 + b] = (dvv + 0.75f * gsum) * (1.0f / 8388608.0f);
    }
}

__global__ __launch_bounds__(256) void merge_fin_kernel(
    const float* __restrict__ pO, const float* __restrict__ pML,
    unsigned short* __restrict__ ao16,
    const float* __restrict__ klp, const float* __restrict__ divp,
    const float* __restrict__ Gp, float* __restrict__ out_tail)
{
    if (blockIdx.x == 256) { finalize_body(klp, divp, Gp, out_tail); return; }
    const int base = blockIdx.x * 512 + threadIdx.x * 2;   // 131072 tasks total
#pragma unroll
    for (int u = 0; u < 2; ++u) {
        const int task = base + u;
        const int g = task >> 2, q = task & 3;
        const int sb = g >> 6, row = g & 63;
        const float2 ml0 = *(const float2*)(pML + (size_t)sb * 256 + row * 2);
        const float2 ml1 = *(const float2*)(pML + (size_t)sb * 256 + 128 + row * 2);
        const float M = fmaxf(ml0.x, ml1.x);
        const float e0 = __expf(ml0.x - M), e1 = __expf(ml1.x - M);
        const float inv = 1.f / fmaf(ml0.y, e0, ml1.y * e1);
        const float f0 = e0 * inv, f1 = e1 * inv;
        const int bh2 = sb >> 4, qt = sb & 15;
        const int b = bh2 >> 3, h = bh2 & 7;
        unsigned short* orow = ao16
            + ((size_t)(b * NL + qt * 64 + row)) * ND + h * NDK + q * 16;
        const float* p0 = pO + (size_t)sb * 8192 + row * 64 + q * 16;
        const float* p1 = p0 + 4096;
#pragma unroll
        for (int j = 0; j < 4; ++j) {
            const float4 a = *(const float4*)(p0 + j * 4);
            const float4 c = *(const float4*)(p1 + j * 4);
            u16x4 ov = { bf16u(a.x * f0 + c.x * f1), bf16u(a.y * f0 + c.y * f1),
                         bf16u(a.z * f0 + c.z * f1), bf16u(a.w * f0 + c.w * f1) };
            *(u16x4*)(orow + j * 4) = ov;
        }
    }
}

// ---------------------------------------------------------------------------
__global__ __launch_bounds__(256) void gemm_single(GemmArgs g)
{
    __shared__ alignas(16) unsigned char smem[20480];
    gemm_body(g, smem);
}

// ---------------------------------------------------------------------------
extern "C" void kernel_launch(void* const* d_in, const int* in_sizes, int n_in,
                              void* d_out, int out_size, void* d_ws, size_t ws_size,
                              hipStream_t stream)
{
    const float* query        = (const float*)d_in[0];
    const float* key          = (const float*)d_in[1];
    const float* value        = (const float*)d_in[2];
    const float* padding_mask = (const float*)d_in[3];
    const float* Wq = (const float*)d_in[4];
    const float* bq = (const float*)d_in[5];
    const float* Wk = (const float*)d_in[6];
    const float* bk = (const float*)d_in[7];
    const float* Wv = (const float*)d_in[8];
    const float* bv = (const float*)d_in[9];
    const float* Wo = (const float*)d_in[10];
    const float* bo = (const float*)d_in[11];
    const float* tok_mu        = (const float*)d_in[12];
    const float* tok_log_var   = (const float*)d_in[13];
    const float* tok_log_prior = (const float*)d_in[14];

    float* ws = (float*)d_ws;
    const size_t FS = 1048576;                       // float-slots per bf16 matrix
    unsigned short* qp16  = (unsigned short*)ws;
    unsigned short* kp16  = (unsigned short*)(ws + FS);
    unsigned short* vtp16 = (unsigned short*)(ws + 2 * FS);
    unsigned short* ao16  = (unsigned short*)(ws + 3 * FS);
    unsigned short* pqx   = (unsigned short*)(ws + 4 * FS);       // 524288 u16
    unsigned short* pkx   = (unsigned short*)(ws + 4 * FS + 262144);
    float* pO   = ws + 4 * FS + 524288;              // 512*2*64*64 = 4194304 f
    float* pML  = pO + 4194304;                      // 512*2*64*2 = 131072 f
    float* klp  = pML + 131072;                      // 256
    float* divp = klp + 256;                         // 256
    float* Gp   = divp + 256;                        // 256*64

    // Launch 1: Q/K/V^T projections + clustering (packed probs, partials)
    GemmArgs gq {query, Wq, bq, qp16, 0.125f, 0, 1, 0, 512, 0};
    GemmArgs gk {key,   Wk, bk, kp16, 1.f,    0, 1, 0, 512, 0};
    GemmArgs gvt{Wv, value, bv, vtp16, 1.f,   0, 1, 1, 4096, 1};
    fused_front<<<dim3(4, 32, 5), 256, 0, stream>>>(
        gq, gk, gvt, query, key, tok_mu, tok_log_var, tok_log_prior,
        pqx, pkx, klp, divp, Gp);

    // Launch 2: flash attention, K-split x2 across blocks
    attn_mfma7_kernel<<<dim3(16, NH, NB * 2), 256, 0, stream>>>(
        qp16, kp16, vtp16, pqx, pkx, padding_mask, pO, pML);

    // Launch 3: merge splits + finalize scalars
    merge_fin_kernel<<<257, 256, 0, stream>>>(
        pO, pML, ao16, klp, divp, Gp, (float*)d_out + (size_t)NB * NL * ND);

    // Launch 4: output projection
    GemmArgs go{ao16, Wo, bo, d_out, 1.f, 1, 0, 0, 512, 0};
    gemm_single<<<dim3(4, 32, 1), 256, 0, stream>>>(go);
}

// Round 10
// 211.587 us; speedup vs baseline: 1.2425x; 1.1433x over previous
//
#include <hip/hip_runtime.h>
#include <hip/hip_bf16.h>
#include <math.h>

// Problem constants: B=4, L=1024, D=512, H=8, C=8, Dk=64
#define NB 4
#define NL 1024
#define ND 512
#define NH 8
#define NC 8
#define NDK 64

static constexpr float KL3_CONST = 115.36544595161891f; // -0.5*(1+ln0.01)*64, per clustering call

typedef __bf16 bf16x8 __attribute__((ext_vector_type(8)));
typedef float  f32x4v __attribute__((ext_vector_type(4)));
typedef unsigned short u16x4 __attribute__((ext_vector_type(4)));
typedef unsigned short u16x8 __attribute__((ext_vector_type(8)));

__device__ __forceinline__ unsigned short bf16u(float f) {
    return __builtin_bit_cast(unsigned short, (__bf16)f);
}

// ---------------------------------------------------------------------------
// GEMM body. 128x128 tile, BK=32, reg prefetch of next k-tile.
// out[row][col] = (Sum_k A[row][k]*W[col][k] + bias) * scale
// ---------------------------------------------------------------------------
struct GemmArgs {
    const void* A; const float* W; const float* bias; void* out;
    float scale; int abf; int obf; int brow; int ostr; int vmap;
};

__device__ __forceinline__ void gemm_body(const GemmArgs& g, unsigned char* smem)
{
    unsigned short* As = (unsigned short*)smem;           // 128*40 u16
    unsigned short* Ws = (unsigned short*)(smem + 10240);
    const int tid = threadIdx.x;
    const int n0 = (g.vmap ? blockIdx.y : blockIdx.x) * 128;
    const int m0 = (g.vmap ? blockIdx.x : blockIdx.y) * 128;

    const int kc = tid & 7;
    const int r0 = tid >> 3;
    const int wave = tid >> 6, lane = tid & 63;
    const int wm = wave >> 1, wn = wave & 1;
    const int r16 = lane & 15, quad = lane >> 4;

    f32x4v acc[4][4];
#pragma unroll
    for (int mi = 0; mi < 4; ++mi)
#pragma unroll
        for (int ni = 0; ni < 4; ++ni)
            acc[mi][ni] = (f32x4v){0.f, 0.f, 0.f, 0.f};

    u16x4 apre[4], wpre[4];
    auto ldA = [&](int k0, int rr) -> u16x4 {
        const int r = r0 + rr * 32;
        if (g.abf) {
            return *(const u16x4*)((const unsigned short*)g.A + (size_t)(m0 + r) * 512 + k0 + kc * 4);
        } else {
            const float4 av = *(const float4*)((const float*)g.A + (size_t)(m0 + r) * 512 + k0 + kc * 4);
            return (u16x4){ bf16u(av.x), bf16u(av.y), bf16u(av.z), bf16u(av.w) };
        }
    };
    auto ldW = [&](int k0, int rr) -> u16x4 {
        const int r = r0 + rr * 32;
        const float4 wv = *(const float4*)(g.W + (size_t)(n0 + r) * 512 + k0 + kc * 4);
        return (u16x4){ bf16u(wv.x), bf16u(wv.y), bf16u(wv.z), bf16u(wv.w) };
    };
#pragma unroll
    for (int rr = 0; rr < 4; ++rr) { apre[rr] = ldA(0, rr); wpre[rr] = ldW(0, rr); }

    for (int k0 = 0; k0 < 512; k0 += 32) {
        __syncthreads();
#pragma unroll
        for (int rr = 0; rr < 4; ++rr) {
            const int r = r0 + rr * 32;
            *(u16x4*)(As + r * 40 + kc * 4) = apre[rr];
            *(u16x4*)(Ws + r * 40 + kc * 4) = wpre[rr];
        }
        __syncthreads();
        if (k0 < 480) {
#pragma unroll
            for (int rr = 0; rr < 4; ++rr) { apre[rr] = ldA(k0 + 32, rr); wpre[rr] = ldW(k0 + 32, rr); }
        }

        bf16x8 af[4], bfr[4];
#pragma unroll
        for (int mi = 0; mi < 4; ++mi)
            af[mi] = *(const bf16x8*)(As + (wm * 64 + mi * 16 + r16) * 40 + quad * 8);
#pragma unroll
        for (int ni = 0; ni < 4; ++ni)
            bfr[ni] = *(const bf16x8*)(Ws + (wn * 64 + ni * 16 + r16) * 40 + quad * 8);
#pragma unroll
        for (int mi = 0; mi < 4; ++mi)
#pragma unroll
            for (int ni = 0; ni < 4; ++ni)
                acc[mi][ni] = __builtin_amdgcn_mfma_f32_16x16x32_bf16(af[mi], bfr[ni], acc[mi][ni], 0, 0, 0);
    }

#pragma unroll
    for (int ni = 0; ni < 4; ++ni) {
        const int col = n0 + wn * 64 + ni * 16 + r16;
        const float bcol = g.brow ? 0.f : g.bias[col];
#pragma unroll
        for (int mi = 0; mi < 4; ++mi) {
#pragma unroll
            for (int i = 0; i < 4; ++i) {
                const int row = m0 + wm * 64 + mi * 16 + quad * 4 + i;
                const float bv = g.brow ? g.bias[row] : bcol;
                const float v = (acc[mi][ni][i] + bv) * g.scale;
                if (g.obf) ((unsigned short*)g.out)[(size_t)row * g.ostr + col] = bf16u(v);
                else       ((float*)g.out)[(size_t)row * g.ostr + col] = v;
            }
        }
    }
}

// ---------------------------------------------------------------------------
// Cluster body: fp32 probs + per-block kl/div/Gram partials.
// block = (side=z-3, bh=blockIdx.y, 256 rows at blockIdx.x*256). 256 threads.
// ---------------------------------------------------------------------------
__device__ __forceinline__ void cluster_body(
    const float* __restrict__ query, const float* __restrict__ key,
    const float* __restrict__ tok_mu, const float* __restrict__ tok_log_var,
    const float* __restrict__ tok_log_prior,
    float* __restrict__ probs_q, float* __restrict__ probs_k,
    float* __restrict__ klp, float* __restrict__ divp, float* __restrict__ Gp,
    unsigned char* smem)
{
    float* mu_s    = (float*)smem;                 // 512 f
    float* iv_s    = (float*)(smem + 2048);        // 512 f
    float* Pl      = (float*)(smem + 4096);        // 256*9 f
    float* Gpart   = (float*)(smem + 13312);       // 4*64 f
    float* red_s   = (float*)(smem + 14336);       // 8 f
    float* lvsum_s = (float*)(smem + 14368);
    float* alpha_s = (float*)(smem + 14400);
    float* logp_s  = (float*)(smem + 14432);
    float* prior_s = (float*)(smem + 14464);

    const int tid  = threadIdx.x;
    const int bh   = blockIdx.y;
    const int b    = bh >> 3, h = bh & 7;
    const int side = blockIdx.z - 3;
    const int blocklin = side * 128 + bh * 4 + blockIdx.x;
    const float* src = side ? key : query;
    float* probs_out = side ? probs_k : probs_q;

    for (int i = tid; i < 512; i += 256) {
        mu_s[i] = tok_mu[h * 512 + i];
        float lv = tok_log_var[h * 512 + i];
        iv_s[i] = __expf(-lv);
    }
    if (tid < 8) {
        float ls = 0.f, al = 0.f;
        for (int d = 0; d < 64; ++d) {
            float lv = tok_log_var[(h * 8 + tid) * 64 + d];
            ls += lv;
            al += 0.01f * __expf(-lv) + lv;
        }
        lvsum_s[tid] = ls; alpha_s[tid] = al;
    }
    if (tid == 0) {
        float lp[8]; float mx = -1e30f;
        for (int c = 0; c < 8; ++c) { lp[c] = tok_log_prior[h * 8 + c]; mx = fmaxf(mx, lp[c]); }
        float se = 0.f;
        for (int c = 0; c < 8; ++c) se += __expf(lp[c] - mx);
        float lse = mx + __logf(se);
        for (int c = 0; c < 8; ++c) { logp_s[c] = lp[c] - lse; prior_s[c] = __expf(lp[c] - lse); }
    }
    __syncthreads();

    const int l = blockIdx.x * 256 + tid;
    const float4* xp = (const float4*)(src + ((size_t)(b * NL + l)) * ND + h * NDK);
    float4 xr[16];
#pragma unroll
    for (int i = 0; i < 16; ++i) xr[i] = xp[i];

    float ms[8];
#pragma unroll
    for (int c = 0; c < 8; ++c) {
        const float4* mc = (const float4*)(mu_s + c * 64);
        const float4* ic = (const float4*)(iv_s + c * 64);
        float s = 0.f;
#pragma unroll
        for (int i = 0; i < 16; ++i) {
            float4 m4 = mc[i], v4 = ic[i], x4 = xr[i];
            float dx = x4.x - m4.x; s = fmaf(dx * dx, v4.x, s);
            float dy = x4.y - m4.y; s = fmaf(dy * dy, v4.y, s);
            float dz = x4.z - m4.z; s = fmaf(dz * dz, v4.z, s);
            float dw = x4.w - m4.w; s = fmaf(dw * dw, v4.w, s);
        }
        ms[c] = s;
    }

    float lpdf[8]; float mx = -1e30f;
#pragma unroll
    for (int c = 0; c < 8; ++c) {
        lpdf[c] = -0.5f * (ms[c] + lvsum_s[c]) + logp_s[c];
        mx = fmaxf(mx, lpdf[c]);
    }
    float e[8]; float se = 0.f;
#pragma unroll
    for (int c = 0; c < 8; ++c) { e[c] = __expf(lpdf[c] - mx); se += e[c]; }
    float lse = __logf(se);
    float inv = 1.f / se;
    float p[8]; float kl1 = 0.f, kl2 = 0.f, sqq = 0.f;
#pragma unroll
    for (int c = 0; c < 8; ++c) {
        p[c] = e[c] * inv;
        float logprob = lpdf[c] - mx - lse;
        kl1 += prior_s[c] * (logp_s[c] - logprob);
        kl2 += p[c] * (ms[c] + alpha_s[c]);
        sqq = fmaf(p[c], p[c], sqq);
    }

    float* po = probs_out + ((size_t)((b * NH + h) * NL + l)) * NC;
    ((float4*)po)[0] = make_float4(p[0], p[1], p[2], p[3]);
    ((float4*)po)[1] = make_float4(p[4], p[5], p[6], p[7]);
#pragma unroll
    for (int c = 0; c < 8; ++c) Pl[tid * 9 + c] = p[c];

    float dterm = 1.25f * (sqq - 1.f) * (sqq - 1.f) - 0.75f * sqq * sqq;
    float klv = kl1 + 0.5f * kl2;
    __syncthreads();

    {
        int qt = tid >> 6, pos = tid & 63, c1 = pos >> 3, c2 = pos & 7;
        float g = 0.f;
        for (int i = 0; i < 64; ++i) {
            int ll = qt * 64 + i;
            g = fmaf(Pl[ll * 9 + c1], Pl[ll * 9 + c2], g);
        }
        Gpart[qt * 64 + pos] = g;
    }

#pragma unroll
    for (int o = 32; o > 0; o >>= 1) {
        klv   += __shfl_down(klv, o);
        dterm += __shfl_down(dterm, o);
    }
    if ((tid & 63) == 0) { red_s[tid >> 6] = klv; red_s[4 + (tid >> 6)] = dterm; }
    __syncthreads();
    if (tid == 0) {
        klp[blocklin]  = red_s[0] + red_s[1] + red_s[2] + red_s[3];
        divp[blocklin] = red_s[4] + red_s[5] + red_s[6] + red_s[7];
    }
    if (tid < 64)
        Gp[(size_t)blocklin * 64 + tid] =
            Gpart[tid] + Gpart[64 + tid] + Gpart[128 + tid] + Gpart[192 + tid];
}

// ---------------------------------------------------------------------------
// Front launch: z 0..2 = Q/K/V^T projections, z 3..4 = clustering (side 0/1).
// grid: (4, 32, 5)  block: 256
// ---------------------------------------------------------------------------
__global__ __launch_bounds__(256) void fused_front(
    GemmArgs g0, GemmArgs g1, GemmArgs g2,
    const float* query, const float* key,
    const float* tok_mu, const float* tok_log_var, const float* tok_log_prior,
    float* probs_q, float* probs_k,
    float* klp, float* divp, float* Gp)
{
    __shared__ alignas(16) unsigned char smem[20480];
    if (blockIdx.z >= 3) {
        cluster_body(query, key, tok_mu, tok_log_var, tok_log_prior,
                     probs_q, probs_k, klp, divp, Gp, smem);
        return;
    }
    GemmArgs g = (blockIdx.z == 0) ? g0 : ((blockIdx.z == 1) ? g1 : g2);
    gemm_body(g, smem);
}

// ---------------------------------------------------------------------------
// MFMA flash attention v3 (PROVEN BEST: 53 us): 32 q-rows/block, 128 threads
// (2 waves x 16-row strips), each wave covers ALL keys; 16 K-tiles of 64.
// K and V^T cooperatively staged in LDS per tile; pk transposed to LDS per
// tile; online softmax in C-layout; P' via per-wave LDS round-trip.
// grid: (32, 8, 4)  block: 128.  LDS ~25KB.
// ---------------------------------------------------------------------------
#define APAD 72

__global__ __launch_bounds__(128) void attn_mfma3_kernel(
    const unsigned short* __restrict__ qp16, const unsigned short* __restrict__ kp16,
    const unsigned short* __restrict__ vtp16,
    const float* __restrict__ probs_q, const float* __restrict__ probs_k,
    const float* __restrict__ padding_mask, unsigned short* __restrict__ ao16)
{
    const int tid = threadIdx.x, lane = tid & 63, w = tid >> 6;
    const int r16 = lane & 15, quad = lane >> 4;
    const int b = blockIdx.z, h = blockIdx.y;
    const int qbase = blockIdx.x * 32;

    __shared__ alignas(16) unsigned short Ks[64 * APAD];
    __shared__ alignas(16) unsigned short Vt[64 * APAD];   // [dim][key]
    __shared__ alignas(16) unsigned short Ps[2][16 * APAD];
    __shared__ float pk_s[8 * 65];                         // [c][key] per tile
    __shared__ float pm_s[64];

    bf16x8 qa[2];
    {
        const unsigned short* qrow = qp16 + ((size_t)(b * NL + qbase + w * 16 + r16)) * ND + h * NDK;
        qa[0] = *(const bf16x8*)(qrow + quad * 8);
        qa[1] = *(const bf16x8*)(qrow + 32 + quad * 8);
    }
    float pq[4][8];
#pragma unroll
    for (int i = 0; i < 4; ++i) {
        const float* pr = probs_q + ((size_t)((b * NH + h) * NL + qbase + w * 16 + quad * 4 + i)) * NC;
        float4 a = ((const float4*)pr)[0], c = ((const float4*)pr)[1];
        pq[i][0] = a.x; pq[i][1] = a.y; pq[i][2] = a.z; pq[i][3] = a.w;
        pq[i][4] = c.x; pq[i][5] = c.y; pq[i][6] = c.z; pq[i][7] = c.w;
    }

    f32x4v oacc[4];
#pragma unroll
    for (int n = 0; n < 4; ++n) oacc[n] = (f32x4v){0.f, 0.f, 0.f, 0.f};
    float m_i[4] = {-1e30f, -1e30f, -1e30f, -1e30f};
    float l_i[4] = {0.f, 0.f, 0.f, 0.f};

    for (int kt = 0; kt < 16; ++kt) {
        const int key0 = kt * 64;
        __syncthreads();   // all reads of prev tile done

        // ---- stage K [key][dim], Vt [dim][key], pk (transposed), pm ----
#pragma unroll
        for (int i = 0; i < 4; ++i) {
            const int c = i * 128 + tid;          // 512 chunks of 8 u16
            const int row = c >> 3, c8 = c & 7;
            u16x8 kv = *(const u16x8*)(kp16 + ((size_t)(b * NL + key0 + row)) * ND + h * NDK + c8 * 8);
            *(u16x8*)(Ks + row * APAD + c8 * 8) = kv;
            u16x8 vv = *(const u16x8*)(vtp16 + ((size_t)(h * 64 + row)) * (NB * NL) + b * NL + key0 + c8 * 8);
            *(u16x8*)(Vt + row * APAD + c8 * 8) = vv;
        }
        {
            const int key = tid >> 1, half = tid & 1;
            float4 p = *(const float4*)(probs_k + ((size_t)((b * NH + h) * NL + key0 + key)) * NC + half * 4);
            pk_s[(half * 4 + 0) * 65 + key] = p.x;
            pk_s[(half * 4 + 1) * 65 + key] = p.y;
            pk_s[(half * 4 + 2) * 65 + key] = p.z;
            pk_s[(half * 4 + 3) * 65 + key] = p.w;
        }
        if (tid < 64) pm_s[tid] = padding_mask[b * NL + key0 + tid];
        __syncthreads();

        // ---- S = Q K^T ----
        f32x4v sacc[4];
#pragma unroll
        for (int t = 0; t < 4; ++t) {
            sacc[t] = (f32x4v){0.f, 0.f, 0.f, 0.f};
            bf16x8 kb0 = *(const bf16x8*)(Ks + (t * 16 + r16) * APAD + quad * 8);
            bf16x8 kb1 = *(const bf16x8*)(Ks + (t * 16 + r16) * APAD + 32 + quad * 8);
            sacc[t] = __builtin_amdgcn_mfma_f32_16x16x32_bf16(qa[0], kb0, sacc[t], 0, 0, 0);
            sacc[t] = __builtin_amdgcn_mfma_f32_16x16x32_bf16(qa[1], kb1, sacc[t], 0, 0, 0);
        }

        // ---- sim (fp32 VALU: enters exponent x10000, needs full precision) ----
        float sc[4][4], wgt[4][4];
#pragma unroll
        for (int t = 0; t < 4; ++t) {
            const int keyl = t * 16 + r16;
            float pkc[8];
#pragma unroll
            for (int c = 0; c < 8; ++c) pkc[c] = pk_s[c * 65 + keyl];
            const float pmv = pm_s[keyl];
#pragma unroll
            for (int i = 0; i < 4; ++i) {
                float sim = 0.f;
#pragma unroll
                for (int c = 0; c < 8; ++c) sim = fmaf(pq[i][c], pkc[c], sim);
                float cm = 1.f - sim + pmv;
                cm = fminf(fmaxf(cm, 0.f), 1.f);
                sc[t][i] = sacc[t][i] - 10000.f * cm;
                wgt[t][i] = 1.f - cm;
            }
        }

        // ---- online softmax (row stats over the 16-lane quad group) ----
        float mx[4];
#pragma unroll
        for (int i = 0; i < 4; ++i)
            mx[i] = fmaxf(fmaxf(sc[0][i], sc[1][i]), fmaxf(sc[2][i], sc[3][i]));
#pragma unroll
        for (int o = 1; o < 16; o <<= 1) {
#pragma unroll
            for (int i = 0; i < 4; ++i) mx[i] = fmaxf(mx[i], __shfl_xor(mx[i], o));
        }
        float rr[4];
#pragma unroll
        for (int i = 0; i < 4; ++i) {
            const float mnew = fmaxf(m_i[i], mx[i]);
            rr[i] = __expf(m_i[i] - mnew);
            m_i[i] = mnew;
            l_i[i] *= rr[i];
        }
#pragma unroll
        for (int n = 0; n < 4; ++n) {
            oacc[n][0] *= rr[0]; oacc[n][1] *= rr[1];
            oacc[n][2] *= rr[2]; oacc[n][3] *= rr[3];
        }
        float lad[4] = {0.f, 0.f, 0.f, 0.f};
#pragma unroll
        for (int t = 0; t < 4; ++t) {
#pragma unroll
            for (int i = 0; i < 4; ++i) {
                const float p = __expf(sc[t][i] - m_i[i]);
                lad[i] += p;
                Ps[w][(quad * 4 + i) * APAD + t * 16 + r16] = bf16u(p * wgt[t][i]);
            }
        }
#pragma unroll
        for (int o = 1; o < 16; o <<= 1) {
#pragma unroll
            for (int i = 0; i < 4; ++i) lad[i] += __shfl_xor(lad[i], o);
        }
#pragma unroll
        for (int i = 0; i < 4; ++i) l_i[i] += lad[i];

        // ---- O += P' V ----
        bf16x8 pa0 = *(const bf16x8*)(Ps[w] + r16 * APAD + quad * 8);
        bf16x8 pa1 = *(const bf16x8*)(Ps[w] + r16 * APAD + 32 + quad * 8);
#pragma unroll
        for (int n = 0; n < 4; ++n) {
            bf16x8 vb0 = *(const bf16x8*)(Vt + (n * 16 + r16) * APAD + quad * 8);
            bf16x8 vb1 = *(const bf16x8*)(Vt + (n * 16 + r16) * APAD + 32 + quad * 8);
            oacc[n] = __builtin_amdgcn_mfma_f32_16x16x32_bf16(pa0, vb0, oacc[n], 0, 0, 0);
            oacc[n] = __builtin_amdgcn_mfma_f32_16x16x32_bf16(pa1, vb1, oacc[n], 0, 0, 0);
        }
    }

    // ---- epilogue: O / l, bf16 out ----
#pragma unroll
    for (int i = 0; i < 4; ++i) {
        const float inv = 1.f / l_i[i];
        const int q = qbase + w * 16 + quad * 4 + i;
        unsigned short* orow = ao16 + ((size_t)(b * NL + q)) * ND + h * NDK;
#pragma unroll
        for (int n = 0; n < 4; ++n) orow[n * 16 + r16] = bf16u(oacc[n][i] * inv);
    }
}

// ---------------------------------------------------------------------------
// Back launch: z=0 O-projection, z=1 (block 0,0) finalize.
// ---------------------------------------------------------------------------
__device__ __forceinline__ void finalize_body(
    const float* __restrict__ klp, const float* __restrict__ divp,
    const float* __restrict__ Gp, float* __restrict__ out_tail)
{
    const int tid = threadIdx.x, b = tid >> 6, lane = tid & 63;
    float gsum = 0.f;
#pragma unroll
    for (int s = 0; s < 2; ++s)
#pragma unroll
        for (int h = 0; h < 8; ++h) {
            const int base = s * 128 + (b * 8 + h) * 4;
            float Ge = 0.f;
#pragma unroll
            for (int x = 0; x < 4; ++x) Ge += Gp[(size_t)(base + x) * 64 + lane];
            gsum = fmaf(Ge, Ge, gsum);
        }
    const int s = lane >> 5, rem = lane & 31, h = rem >> 2, x = rem & 3;
    const int idx = s * 128 + (b * 8 + h) * 4 + x;
    float klv = klp[idx];
    float dvv = divp[idx];
#pragma unroll
    for (int o = 32; o > 0; o >>= 1) {
        gsum += __shfl_down(gsum, o);
        klv  += __shfl_down(klv, o);
        dvv  += __shfl_down(dvv, o);
    }
    if (lane == 0) {
        out_tail[b]     = klv * (1.0f / 8192.0f) + 2.0f * KL3_CONST;
        out_tail[4 + b] = (dvv + 0.75f * gsum) * (1.0f / 8388608.0f);
    }
}

__global__ __launch_bounds__(256) void fused_back(
    GemmArgs g0,
    const float* klp, const float* divp, const float* Gp, float* out_tail)
{
    __shared__ alignas(16) unsigned char smem[20480];
    if (blockIdx.z == 1) {
        if (blockIdx.x == 0 && blockIdx.y == 0)
            finalize_body(klp, divp, Gp, out_tail);
        return;
    }
    gemm_body(g0, smem);
}

// ---------------------------------------------------------------------------
extern "C" void kernel_launch(void* const* d_in, const int* in_sizes, int n_in,
                              void* d_out, int out_size, void* d_ws, size_t ws_size,
                              hipStream_t stream)
{
    const float* query        = (const float*)d_in[0];
    const float* key          = (const float*)d_in[1];
    const float* value        = (const float*)d_in[2];
    const float* padding_mask = (const float*)d_in[3];
    const float* Wq = (const float*)d_in[4];
    const float* bq = (const float*)d_in[5];
    const float* Wk = (const float*)d_in[6];
    const float* bk = (const float*)d_in[7];
    const float* Wv = (const float*)d_in[8];
    const float* bv = (const float*)d_in[9];
    const float* Wo = (const float*)d_in[10];
    const float* bo = (const float*)d_in[11];
    const float* tok_mu        = (const float*)d_in[12];
    const float* tok_log_var   = (const float*)d_in[13];
    const float* tok_log_prior = (const float*)d_in[14];

    float* ws = (float*)d_ws;
    const size_t FS = 1048576;                       // float-slots per bf16 matrix
    unsigned short* qp16  = (unsigned short*)ws;
    unsigned short* kp16  = (unsigned short*)(ws + FS);
    unsigned short* vtp16 = (unsigned short*)(ws + 2 * FS);
    unsigned short* ao16  = (unsigned short*)(ws + 3 * FS);
    float* probs_q = ws + 4 * FS;                    // 262144 floats each
    float* probs_k = probs_q + (size_t)NB * NH * NL * NC;
    float* klp     = probs_k + (size_t)NB * NH * NL * NC;   // 256
    float* divp    = klp + 256;                              // 256
    float* Gp      = divp + 256;                             // 256*64

    // Launch 1: Q/K/V^T projections (z 0..2) + clustering (z 3..4)
    GemmArgs gq {query, Wq, bq, qp16, 0.125f, 0, 1, 0, 512, 0};
    GemmArgs gk {key,   Wk, bk, kp16, 1.f,    0, 1, 0, 512, 0};
    GemmArgs gvt{Wv, value, bv, vtp16, 1.f,   0, 1, 1, 4096, 1};
    fused_front<<<dim3(4, 32, 5), 256, 0, stream>>>(
        gq, gk, gvt, query, key, tok_mu, tok_log_var, tok_log_prior,
        probs_q, probs_k, klp, divp, Gp);

    // Launch 2: flash attention (proven v3 structure)
    attn_mfma3_kernel<<<dim3(32, NH, NB), 128, 0, stream>>>(
        qp16, kp16, vtp16, probs_q, probs_k, padding_mask, ao16);

    // Launch 3: O-projection (z=0) + finalize (z=1, block 0,0)
    GemmArgs go{ao16, Wo, bo, d_out, 1.f, 1, 0, 0, 512, 0};
    fused_back<<<dim3(4, 32, 2), 256, 0, stream>>>(
        go, klp, divp, Gp, (float*)d_out + (size_t)NB * NL * ND);
}

// Round 11
// 211.581 us; speedup vs baseline: 1.2425x; 1.0000x over previous
//
#include <hip/hip_runtime.h>
#include <hip/hip_bf16.h>
#include <math.h>

// Problem constants: B=4, L=1024, D=512, H=8, C=8, Dk=64
#define NB 4
#define NL 1024
#define ND 512
#define NH 8
#define NC 8
#define NDK 64

static constexpr float KL3_CONST = 115.36544595161891f; // -0.5*(1+ln0.01)*64, per clustering call

typedef __bf16 bf16x8 __attribute__((ext_vector_type(8)));
typedef float  f32x4v __attribute__((ext_vector_type(4)));
typedef unsigned short u16x4 __attribute__((ext_vector_type(4)));
typedef unsigned short u16x8 __attribute__((ext_vector_type(8)));

__device__ __forceinline__ unsigned short bf16u(float f) {
    return __builtin_bit_cast(unsigned short, (__bf16)f);
}

// ---------------------------------------------------------------------------
// GEMM body v2: 64x128 tile (2x the blocks of 128x128 -> ~4 blocks/CU), BK=32,
// DEPTH-2 register prefetch (two 32-k stages in flight covers ~500cy latency).
// 4 waves; wave w owns m-strip w*16, all 128 n-cols (8 MFMA / 32-k step).
// out[row][col] = (Sum_k A[row][k]*W[col][k] + bias) * scale
// ---------------------------------------------------------------------------
struct GemmArgs {
    const void* A; const float* W; const float* bias; void* out;
    float scale; int abf; int obf; int brow; int ostr; int vmap;
};

__device__ __forceinline__ void gemm_body(const GemmArgs& g, unsigned char* smem)
{
    unsigned short* As = (unsigned short*)smem;           // 64*40 u16 = 5120B
    unsigned short* Ws = (unsigned short*)(smem + 5120);  // 128*40 u16 = 10240B
    const int tid = threadIdx.x;
    int n0, m0;
    if (g.vmap) {   // V^T slice: M=512, N=4096 -> 8 m-tiles x 32 n-tiles
        const int linear = blockIdx.y * 4 + blockIdx.x;   // 0..255
        n0 = (linear & 31) * 128;
        m0 = (linear >> 5) * 64;
    } else {        // M=4096, N=512 -> 64 m-tiles x 4 n-tiles
        n0 = blockIdx.x * 128;
        m0 = blockIdx.y * 64;
    }

    const int w = tid >> 6, lane = tid & 63;
    const int r16 = lane & 15, quad = lane >> 4;
    const int arow = tid >> 2, akc = tid & 3;   // A stage: row 0..63, 8 elems
    const int wrow = tid >> 1, wkc = tid & 1;   // W stage: row 0..127, 16 elems

    f32x4v acc[8];
#pragma unroll
    for (int n = 0; n < 8; ++n) acc[n] = (f32x4v){0.f, 0.f, 0.f, 0.f};

    auto ldA = [&](int k0) -> u16x8 {
        if (g.abf) {
            return *(const u16x8*)((const unsigned short*)g.A + (size_t)(m0 + arow) * 512 + k0 + akc * 8);
        }
        const float* ap = (const float*)g.A + (size_t)(m0 + arow) * 512 + k0 + akc * 8;
        const float4 a0 = *(const float4*)ap, a1 = *(const float4*)(ap + 4);
        return (u16x8){ bf16u(a0.x), bf16u(a0.y), bf16u(a0.z), bf16u(a0.w),
                        bf16u(a1.x), bf16u(a1.y), bf16u(a1.z), bf16u(a1.w) };
    };
    auto ldW = [&](int k0, u16x8* dst) {
        const float* wp = (const float*)g.W + (size_t)(n0 + wrow) * 512 + k0 + wkc * 16;
        const float4 w0 = *(const float4*)wp,       w1 = *(const float4*)(wp + 4);
        const float4 w2 = *(const float4*)(wp + 8), w3 = *(const float4*)(wp + 12);
        dst[0] = (u16x8){ bf16u(w0.x), bf16u(w0.y), bf16u(w0.z), bf16u(w0.w),
                          bf16u(w1.x), bf16u(w1.y), bf16u(w1.z), bf16u(w1.w) };
        dst[1] = (u16x8){ bf16u(w2.x), bf16u(w2.y), bf16u(w2.z), bf16u(w2.w),
                          bf16u(w3.x), bf16u(w3.y), bf16u(w3.z), bf16u(w3.w) };
    };
    auto store_stage = [&](const u16x8& sa, const u16x8* sw) {
        *(u16x8*)(As + arow * 40 + akc * 8) = sa;
        *(u16x8*)(Ws + wrow * 40 + wkc * 16) = sw[0];
        *(u16x8*)(Ws + wrow * 40 + wkc * 16 + 8) = sw[1];
    };
    auto mfma_half = [&]() {
        bf16x8 af = *(const bf16x8*)(As + (w * 16 + r16) * 40 + quad * 8);
#pragma unroll
        for (int ni = 0; ni < 8; ++ni) {
            bf16x8 bfr = *(const bf16x8*)(Ws + (ni * 16 + r16) * 40 + quad * 8);
            acc[ni] = __builtin_amdgcn_mfma_f32_16x16x32_bf16(af, bfr, acc[ni], 0, 0, 0);
        }
    };

    // two stages in flight
    u16x8 sa0 = ldA(0),  sw0[2]; ldW(0, sw0);
    u16x8 sa1 = ldA(32), sw1[2]; ldW(32, sw1);

    for (int k0 = 0; k0 < 512; k0 += 64) {
        __syncthreads();
        store_stage(sa0, sw0);
        __syncthreads();
        if (k0 + 64 < 512) { sa0 = ldA(k0 + 64); ldW(k0 + 64, sw0); }
        mfma_half();

        __syncthreads();
        store_stage(sa1, sw1);
        __syncthreads();
        if (k0 + 96 < 512) { sa1 = ldA(k0 + 96); ldW(k0 + 96, sw1); }
        mfma_half();
    }

#pragma unroll
    for (int ni = 0; ni < 8; ++ni) {
        const int col = n0 + ni * 16 + r16;
        const float bcol = g.brow ? 0.f : g.bias[col];
#pragma unroll
        for (int i = 0; i < 4; ++i) {
            const int row = m0 + w * 16 + quad * 4 + i;
            const float bv = g.brow ? g.bias[row] : bcol;
            const float v = (acc[ni][i] + bv) * g.scale;
            if (g.obf) ((unsigned short*)g.out)[(size_t)row * g.ostr + col] = bf16u(v);
            else       ((float*)g.out)[(size_t)row * g.ostr + col] = v;
        }
    }
}

// ---------------------------------------------------------------------------
// Cluster body: fp32 probs + per-block kl/div/Gram partials. 256 threads.
// linear (0..255): side = linear>>7, bh = (linear&127)>>2, chunk = linear&3.
// ---------------------------------------------------------------------------
__device__ __forceinline__ void cluster_body(
    const float* __restrict__ query, const float* __restrict__ key,
    const float* __restrict__ tok_mu, const float* __restrict__ tok_log_var,
    const float* __restrict__ tok_log_prior,
    float* __restrict__ probs_q, float* __restrict__ probs_k,
    float* __restrict__ klp, float* __restrict__ divp, float* __restrict__ Gp,
    int linear, unsigned char* smem)
{
    float* mu_s    = (float*)smem;                 // 512 f
    float* iv_s    = (float*)(smem + 2048);        // 512 f
    float* Pl      = (float*)(smem + 4096);        // 256*9 f
    float* Gpart   = (float*)(smem + 13312);       // 4*64 f
    float* red_s   = (float*)(smem + 14336);       // 8 f
    float* lvsum_s = (float*)(smem + 14368);
    float* alpha_s = (float*)(smem + 14400);
    float* logp_s  = (float*)(smem + 14432);
    float* prior_s = (float*)(smem + 14464);

    const int tid  = threadIdx.x;
    const int side = linear >> 7;
    const int rem  = linear & 127;
    const int bh   = rem >> 2, chunk = rem & 3;
    const int b    = bh >> 3, h = bh & 7;
    const int blocklin = side * 128 + bh * 4 + chunk;
    const float* src = side ? key : query;
    float* probs_out = side ? probs_k : probs_q;

    for (int i = tid; i < 512; i += 256) {
        mu_s[i] = tok_mu[h * 512 + i];
        float lv = tok_log_var[h * 512 + i];
        iv_s[i] = __expf(-lv);
    }
    if (tid < 8) {
        float ls = 0.f, al = 0.f;
        for (int d = 0; d < 64; ++d) {
            float lv = tok_log_var[(h * 8 + tid) * 64 + d];
            ls += lv;
            al += 0.01f * __expf(-lv) + lv;
        }
        lvsum_s[tid] = ls; alpha_s[tid] = al;
    }
    if (tid == 0) {
        float lp[8]; float mx = -1e30f;
        for (int c = 0; c < 8; ++c) { lp[c] = tok_log_prior[h * 8 + c]; mx = fmaxf(mx, lp[c]); }
        float se = 0.f;
        for (int c = 0; c < 8; ++c) se += __expf(lp[c] - mx);
        float lse = mx + __logf(se);
        for (int c = 0; c < 8; ++c) { logp_s[c] = lp[c] - lse; prior_s[c] = __expf(lp[c] - lse); }
    }
    __syncthreads();

    const int l = chunk * 256 + tid;
    const float4* xp = (const float4*)(src + ((size_t)(b * NL + l)) * ND + h * NDK);
    float4 xr[16];
#pragma unroll
    for (int i = 0; i < 16; ++i) xr[i] = xp[i];

    float ms[8];
#pragma unroll
    for (int c = 0; c < 8; ++c) {
        const float4* mc = (const float4*)(mu_s + c * 64);
        const float4* ic = (const float4*)(iv_s + c * 64);
        float s = 0.f;
#pragma unroll
        for (int i = 0; i < 16; ++i) {
            float4 m4 = mc[i], v4 = ic[i], x4 = xr[i];
            float dx = x4.x - m4.x; s = fmaf(dx * dx, v4.x, s);
            float dy = x4.y - m4.y; s = fmaf(dy * dy, v4.y, s);
            float dz = x4.z - m4.z; s = fmaf(dz * dz, v4.z, s);
            float dw = x4.w - m4.w; s = fmaf(dw * dw, v4.w, s);
        }
        ms[c] = s;
    }

    float lpdf[8]; float mx = -1e30f;
#pragma unroll
    for (int c = 0; c < 8; ++c) {
        lpdf[c] = -0.5f * (ms[c] + lvsum_s[c]) + logp_s[c];
        mx = fmaxf(mx, lpdf[c]);
    }
    float e[8]; float se = 0.f;
#pragma unroll
    for (int c = 0; c < 8; ++c) { e[c] = __expf(lpdf[c] - mx); se += e[c]; }
    float lse = __logf(se);
    float inv = 1.f / se;
    float p[8]; float kl1 = 0.f, kl2 = 0.f, sqq = 0.f;
#pragma unroll
    for (int c = 0; c < 8; ++c) {
        p[c] = e[c] * inv;
        float logprob = lpdf[c] - mx - lse;
        kl1 += prior_s[c] * (logp_s[c] - logprob);
        kl2 += p[c] * (ms[c] + alpha_s[c]);
        sqq = fmaf(p[c], p[c], sqq);
    }

    float* po = probs_out + ((size_t)((b * NH + h) * NL + l)) * NC;
    ((float4*)po)[0] = make_float4(p[0], p[1], p[2], p[3]);
    ((float4*)po)[1] = make_float4(p[4], p[5], p[6], p[7]);
#pragma unroll
    for (int c = 0; c < 8; ++c) Pl[tid * 9 + c] = p[c];

    float dterm = 1.25f * (sqq - 1.f) * (sqq - 1.f) - 0.75f * sqq * sqq;
    float klv = kl1 + 0.5f * kl2;
    __syncthreads();

    {
        int qt = tid >> 6, pos = tid & 63, c1 = pos >> 3, c2 = pos & 7;
        float g = 0.f;
        for (int i = 0; i < 64; ++i) {
            int ll = qt * 64 + i;
            g = fmaf(Pl[ll * 9 + c1], Pl[ll * 9 + c2], g);
        }
        Gpart[qt * 64 + pos] = g;
    }

#pragma unroll
    for (int o = 32; o > 0; o >>= 1) {
        klv   += __shfl_down(klv, o);
        dterm += __shfl_down(dterm, o);
    }
    if ((tid & 63) == 0) { red_s[tid >> 6] = klv; red_s[4 + (tid >> 6)] = dterm; }
    __syncthreads();
    if (tid == 0) {
        klp[blocklin]  = red_s[0] + red_s[1] + red_s[2] + red_s[3];
        divp[blocklin] = red_s[4] + red_s[5] + red_s[6] + red_s[7];
    }
    if (tid < 64)
        Gp[(size_t)blocklin * 64 + tid] =
            Gpart[tid] + Gpart[64 + tid] + Gpart[128 + tid] + Gpart[192 + tid];
}

// ---------------------------------------------------------------------------
// Front launch: z 0..2 = Q/K/V^T projections, z=3 = clustering (both sides).
// grid: (4, 64, 4)  block: 256
// ---------------------------------------------------------------------------
__global__ __launch_bounds__(256) void fused_front(
    GemmArgs g0, GemmArgs g1, GemmArgs g2,
    const float* query, const float* key,
    const float* tok_mu, const float* tok_log_var, const float* tok_log_prior,
    float* probs_q, float* probs_k,
    float* klp, float* divp, float* Gp)
{
    __shared__ alignas(16) unsigned char smem[15488];
    if (blockIdx.z == 3) {
        const int linear = blockIdx.y * 4 + blockIdx.x;   // 0..255
        cluster_body(query, key, tok_mu, tok_log_var, tok_log_prior,
                     probs_q, probs_k, klp, divp, Gp, linear, smem);
        return;
    }
    GemmArgs g = (blockIdx.z == 0) ? g0 : ((blockIdx.z == 1) ? g1 : g2);
    gemm_body(g, smem);
}

// ---------------------------------------------------------------------------
// MFMA flash attention v3 + K-SPLIT x2 across blocks. Per-tile code is the
// PROVEN v3 structure (K/Vt/pk LDS-staged); each block does 8 tiles (half the
// keys) and writes fp32 (m,l,O) partials. grid: (32, 8, 8) block: 128.
// z: b = z>>1, s = z&1.  4096 waves (2x v3).
// ---------------------------------------------------------------------------
#define APAD 72

__global__ __launch_bounds__(128) void attn_mfma3s_kernel(
    const unsigned short* __restrict__ qp16, const unsigned short* __restrict__ kp16,
    const unsigned short* __restrict__ vtp16,
    const float* __restrict__ probs_q, const float* __restrict__ probs_k,
    const float* __restrict__ padding_mask,
    float* __restrict__ pO, float* __restrict__ pML)
{
    const int tid = threadIdx.x, lane = tid & 63, w = tid >> 6;
    const int r16 = lane & 15, quad = lane >> 4;
    const int b = blockIdx.z >> 1, s = blockIdx.z & 1;
    const int h = blockIdx.y;
    const int qt = blockIdx.x;
    const int qbase = qt * 32;
    const int sb = ((b * 8 + h) << 5) | qt;               // 0..1023

    __shared__ alignas(16) unsigned short Ks[64 * APAD];
    __shared__ alignas(16) unsigned short Vt[64 * APAD];   // [dim][key]
    __shared__ alignas(16) unsigned short Ps[2][16 * APAD];
    __shared__ float pk_s[8 * 65];                         // [c][key] per tile
    __shared__ float pm_s[64];

    bf16x8 qa[2];
    {
        const unsigned short* qrow = qp16 + ((size_t)(b * NL + qbase + w * 16 + r16)) * ND + h * NDK;
        qa[0] = *(const bf16x8*)(qrow + quad * 8);
        qa[1] = *(const bf16x8*)(qrow + 32 + quad * 8);
    }
    float pq[4][8];
#pragma unroll
    for (int i = 0; i < 4; ++i) {
        const float* pr = probs_q + ((size_t)((b * NH + h) * NL + qbase + w * 16 + quad * 4 + i)) * NC;
        float4 a = ((const float4*)pr)[0], c = ((const float4*)pr)[1];
        pq[i][0] = a.x; pq[i][1] = a.y; pq[i][2] = a.z; pq[i][3] = a.w;
        pq[i][4] = c.x; pq[i][5] = c.y; pq[i][6] = c.z; pq[i][7] = c.w;
    }

    f32x4v oacc[4];
#pragma unroll
    for (int n = 0; n < 4; ++n) oacc[n] = (f32x4v){0.f, 0.f, 0.f, 0.f};
    float m_i[4] = {-1e30f, -1e30f, -1e30f, -1e30f};
    float l_i[4] = {0.f, 0.f, 0.f, 0.f};

    for (int kt = 0; kt < 8; ++kt) {
        const int key0 = s * 512 + kt * 64;
        __syncthreads();   // all reads of prev tile done

        // ---- stage K [key][dim], Vt [dim][key], pk (transposed), pm ----
#pragma unroll
        for (int i = 0; i < 4; ++i) {
            const int c = i * 128 + tid;          // 512 chunks of 8 u16
            const int row = c >> 3, c8 = c & 7;
            u16x8 kv = *(const u16x8*)(kp16 + ((size_t)(b * NL + key0 + row)) * ND + h * NDK + c8 * 8);
            *(u16x8*)(Ks + row * APAD + c8 * 8) = kv;
            u16x8 vv = *(const u16x8*)(vtp16 + ((size_t)(h * 64 + row)) * (NB * NL) + b * NL + key0 + c8 * 8);
            *(u16x8*)(Vt + row * APAD + c8 * 8) = vv;
        }
        {
            const int key = tid >> 1, half = tid & 1;
            float4 p = *(const float4*)(probs_k + ((size_t)((b * NH + h) * NL + key0 + key)) * NC + half * 4);
            pk_s[(half * 4 + 0) * 65 + key] = p.x;
            pk_s[(half * 4 + 1) * 65 + key] = p.y;
            pk_s[(half * 4 + 2) * 65 + key] = p.z;
            pk_s[(half * 4 + 3) * 65 + key] = p.w;
        }
        if (tid < 64) pm_s[tid] = padding_mask[b * NL + key0 + tid];
        __syncthreads();

        // ---- S = Q K^T ----
        f32x4v sacc[4];
#pragma unroll
        for (int t = 0; t < 4; ++t) {
            sacc[t] = (f32x4v){0.f, 0.f, 0.f, 0.f};
            bf16x8 kb0 = *(const bf16x8*)(Ks + (t * 16 + r16) * APAD + quad * 8);
            bf16x8 kb1 = *(const bf16x8*)(Ks + (t * 16 + r16) * APAD + 32 + quad * 8);
            sacc[t] = __builtin_amdgcn_mfma_f32_16x16x32_bf16(qa[0], kb0, sacc[t], 0, 0, 0);
            sacc[t] = __builtin_amdgcn_mfma_f32_16x16x32_bf16(qa[1], kb1, sacc[t], 0, 0, 0);
        }

        // ---- sim (fp32 VALU: enters exponent x10000, needs full precision) ----
        float sc[4][4], wgt[4][4];
#pragma unroll
        for (int t = 0; t < 4; ++t) {
            const int keyl = t * 16 + r16;
            float pkc[8];
#pragma unroll
            for (int c = 0; c < 8; ++c) pkc[c] = pk_s[c * 65 + keyl];
            const float pmv = pm_s[keyl];
#pragma unroll
            for (int i = 0; i < 4; ++i) {
                float sim = 0.f;
#pragma unroll
                for (int c = 0; c < 8; ++c) sim = fmaf(pq[i][c], pkc[c], sim);
                float cm = 1.f - sim + pmv;
                cm = fminf(fmaxf(cm, 0.f), 1.f);
                sc[t][i] = sacc[t][i] - 10000.f * cm;
                wgt[t][i] = 1.f - cm;
            }
        }

        // ---- online softmax (row stats over the 16-lane quad group) ----
        float mx[4];
#pragma unroll
        for (int i = 0; i < 4; ++i)
            mx[i] = fmaxf(fmaxf(sc[0][i], sc[1][i]), fmaxf(sc[2][i], sc[3][i]));
#pragma unroll
        for (int o = 1; o < 16; o <<= 1) {
#pragma unroll
            for (int i = 0; i < 4; ++i) mx[i] = fmaxf(mx[i], __shfl_xor(mx[i], o));
        }
        float rr[4];
#pragma unroll
        for (int i = 0; i < 4; ++i) {
            const float mnew = fmaxf(m_i[i], mx[i]);
            rr[i] = __expf(m_i[i] - mnew);
            m_i[i] = mnew;
            l_i[i] *= rr[i];
        }
#pragma unroll
        for (int n = 0; n < 4; ++n) {
            oacc[n][0] *= rr[0]; oacc[n][1] *= rr[1];
            oacc[n][2] *= rr[2]; oacc[n][3] *= rr[3];
        }
        float lad[4] = {0.f, 0.f, 0.f, 0.f};
#pragma unroll
        for (int t = 0; t < 4; ++t) {
#pragma unroll
            for (int i = 0; i < 4; ++i) {
                const float p = __expf(sc[t][i] - m_i[i]);
                lad[i] += p;
                Ps[w][(quad * 4 + i) * APAD + t * 16 + r16] = bf16u(p * wgt[t][i]);
            }
        }
#pragma unroll
        for (int o = 1; o < 16; o <<= 1) {
#pragma unroll
            for (int i = 0; i < 4; ++i) lad[i] += __shfl_xor(lad[i], o);
        }
#pragma unroll
        for (int i = 0; i < 4; ++i) l_i[i] += lad[i];

        // ---- O += P' V ----
        bf16x8 pa0 = *(const bf16x8*)(Ps[w] + r16 * APAD + quad * 8);
        bf16x8 pa1 = *(const bf16x8*)(Ps[w] + r16 * APAD + 32 + quad * 8);
#pragma unroll
        for (int n = 0; n < 4; ++n) {
            bf16x8 vb0 = *(const bf16x8*)(Vt + (n * 16 + r16) * APAD + quad * 8);
            bf16x8 vb1 = *(const bf16x8*)(Vt + (n * 16 + r16) * APAD + 32 + quad * 8);
            oacc[n] = __builtin_amdgcn_mfma_f32_16x16x32_bf16(pa0, vb0, oacc[n], 0, 0, 0);
            oacc[n] = __builtin_amdgcn_mfma_f32_16x16x32_bf16(pa1, vb1, oacc[n], 0, 0, 0);
        }
    }

    // ---- write fp32 partials ----
    float* po = pO + ((size_t)sb * 2 + s) * 2048;
#pragma unroll
    for (int i = 0; i < 4; ++i) {
        const int row = w * 16 + quad * 4 + i;
#pragma unroll
        for (int n = 0; n < 4; ++n)
            po[row * 64 + n * 16 + r16] = oacc[n][i];
    }
    if (r16 == 0) {
        float* pml = pML + ((size_t)sb * 2 + s) * 64;
#pragma unroll
        for (int i = 0; i < 4; ++i) {
            const int row = w * 16 + quad * 4 + i;
            pml[row * 2]     = m_i[i];
            pml[row * 2 + 1] = l_i[i];
        }
    }
}

// ---------------------------------------------------------------------------
// Merge launch: blocks 0..1023 merge the 2 K-splits -> ao16 (bf16);
// block 1024 computes the kl/div scalars.
// ---------------------------------------------------------------------------
__device__ __forceinline__ void finalize_body(
    const float* __restrict__ klp, const float* __restrict__ divp,
    const float* __restrict__ Gp, float* __restrict__ out_tail)
{
    const int tid = threadIdx.x, b = tid >> 6, lane = tid & 63;
    float gsum = 0.f;
#pragma unroll
    for (int s = 0; s < 2; ++s)
#pragma unroll
        for (int h = 0; h < 8; ++h) {
            const int base = s * 128 + (b * 8 + h) * 4;
            float Ge = 0.f;
#pragma unroll
            for (int x = 0; x < 4; ++x) Ge += Gp[(size_t)(base + x) * 64 + lane];
            gsum = fmaf(Ge, Ge, gsum);
        }
    const int s = lane >> 5, rem = lane & 31, h = rem >> 2, x = rem & 3;
    const int idx = s * 128 + (b * 8 + h) * 4 + x;
    float klv = klp[idx];
    float dvv = divp[idx];
#pragma unroll
    for (int o = 32; o > 0; o >>= 1) {
        gsum += __shfl_down(gsum, o);
        klv  += __shfl_down(klv, o);
        dvv  += __shfl_down(dvv, o);
    }
    if (lane == 0) {
        out_tail[b]     = klv * (1.0f / 8192.0f) + 2.0f * KL3_CONST;
        out_tail[4 + b] = (dvv + 0.75f * gsum) * (1.0f / 8388608.0f);
    }
}

__global__ __launch_bounds__(256) void merge_fin_kernel(
    const float* __restrict__ pO, const float* __restrict__ pML,
    unsigned short* __restrict__ ao16,
    const float* __restrict__ klp, const float* __restrict__ divp,
    const float* __restrict__ Gp, float* __restrict__ out_tail)
{
    if (blockIdx.x == 1024) { finalize_body(klp, divp, Gp, out_tail); return; }
    const int gid = blockIdx.x * 256 + threadIdx.x;      // 262144 tasks
    const int sb = gid >> 8, rem = gid & 255;
    const int row = rem >> 3, d0 = (rem & 7) * 8;

    const float2 ml0 = *(const float2*)(pML + ((size_t)sb * 2 + 0) * 64 + row * 2);
    const float2 ml1 = *(const float2*)(pML + ((size_t)sb * 2 + 1) * 64 + row * 2);
    const float M = fmaxf(ml0.x, ml1.x);
    const float e0 = __expf(ml0.x - M), e1 = __expf(ml1.x - M);
    const float inv = 1.f / fmaf(ml0.y, e0, ml1.y * e1);
    const float f0 = e0 * inv, f1 = e1 * inv;

    const float* p0 = pO + ((size_t)sb * 2 + 0) * 2048 + row * 64 + d0;
    const float* p1 = pO + ((size_t)sb * 2 + 1) * 2048 + row * 64 + d0;
    const int qt = sb & 31, bh = sb >> 5, h = bh & 7, b = bh >> 3;
    unsigned short* orow = ao16 + ((size_t)(b * NL + qt * 32 + row)) * ND + h * NDK + d0;

    const float4 a0 = *(const float4*)p0,       a1 = *(const float4*)(p0 + 4);
    const float4 c0 = *(const float4*)p1,       c1 = *(const float4*)(p1 + 4);
    u16x8 ov = { bf16u(a0.x * f0 + c0.x * f1), bf16u(a0.y * f0 + c0.y * f1),
                 bf16u(a0.z * f0 + c0.z * f1), bf16u(a0.w * f0 + c0.w * f1),
                 bf16u(a1.x * f0 + c1.x * f1), bf16u(a1.y * f0 + c1.y * f1),
                 bf16u(a1.z * f0 + c1.z * f1), bf16u(a1.w * f0 + c1.w * f1) };
    *(u16x8*)orow = ov;
}

// ---------------------------------------------------------------------------
__global__ __launch_bounds__(256) void gemm_single(GemmArgs g)
{
    __shared__ alignas(16) unsigned char smem[15488];
    gemm_body(g, smem);
}

// ---------------------------------------------------------------------------
extern "C" void kernel_launch(void* const* d_in, const int* in_sizes, int n_in,
                              void* d_out, int out_size, void* d_ws, size_t ws_size,
                              hipStream_t stream)
{
    const float* query        = (const float*)d_in[0];
    const float* key          = (const float*)d_in[1];
    const float* value        = (const float*)d_in[2];
    const float* padding_mask = (const float*)d_in[3];
    const float* Wq = (const float*)d_in[4];
    const float* bq = (const float*)d_in[5];
    const float* Wk = (const float*)d_in[6];
    const float* bk = (const float*)d_in[7];
    const float* Wv = (const float*)d_in[8];
    const float* bv = (const float*)d_in[9];
    const float* Wo = (const float*)d_in[10];
    const float* bo = (const float*)d_in[11];
    const float* tok_mu        = (const float*)d_in[12];
    const float* tok_log_var   = (const float*)d_in[13];
    const float* tok_log_prior = (const float*)d_in[14];

    float* ws = (float*)d_ws;
    const size_t FS = 1048576;                       // float-slots per bf16 matrix
    unsigned short* qp16  = (unsigned short*)ws;
    unsigned short* kp16  = (unsigned short*)(ws + FS);
    unsigned short* vtp16 = (unsigned short*)(ws + 2 * FS);
    unsigned short* ao16  = (unsigned short*)(ws + 3 * FS);
    float* probs_q = ws + 4 * FS;                    // 262144 floats each
    float* probs_k = probs_q + (size_t)NB * NH * NL * NC;
    float* pO      = probs_k + (size_t)NB * NH * NL * NC;   // 1024*2*2048 = 4194304
    float* pML     = pO + 4194304;                           // 1024*2*64 = 131072
    float* klp     = pML + 131072;                           // 256
    float* divp    = klp + 256;                              // 256
    float* Gp      = divp + 256;                             // 256*64

    // Launch 1: Q/K/V^T projections (z 0..2) + clustering (z=3)
    GemmArgs gq {query, Wq, bq, qp16, 0.125f, 0, 1, 0, 512, 0};
    GemmArgs gk {key,   Wk, bk, kp16, 1.f,    0, 1, 0, 512, 0};
    GemmArgs gvt{Wv, value, bv, vtp16, 1.f,   0, 1, 1, 4096, 1};
    fused_front<<<dim3(4, 64, 4), 256, 0, stream>>>(
        gq, gk, gvt, query, key, tok_mu, tok_log_var, tok_log_prior,
        probs_q, probs_k, klp, divp, Gp);

    // Launch 2: flash attention (proven v3 tile code, K-split x2 across blocks)
    attn_mfma3s_kernel<<<dim3(32, NH, NB * 2), 128, 0, stream>>>(
        qp16, kp16, vtp16, probs_q, probs_k, padding_mask, pO, pML);

    // Launch 3: merge splits (1024 blocks) + finalize scalars (block 1024)
    merge_fin_kernel<<<1025, 256, 0, stream>>>(
        pO, pML, ao16, klp, divp, Gp, (float*)d_out + (size_t)NB * NL * ND);

    // Launch 4: output projection
    GemmArgs go{ao16, Wo, bo, d_out, 1.f, 1, 0, 0, 512, 0};
    gemm_single<<<dim3(4, 64, 1), 256, 0, stream>>>(go);
}